// Round 2
// baseline (6672.964 us; speedup 1.0000x reference)
//
#include <hip/hip_runtime.h>
#include <math.h>

// Problem constants
#define NROWS 65536      // 32*2048
#define DDIM  768
#define KCODES 1024
#define NCB   8          // code blocks (KCODES / BK)
#define BM    128        // rows per block
#define BK    128        // codes per block
#define DC    16         // D-chunk staged in LDS
#define NCH   (DDIM / DC)
#define LDST  132        // padded LDS stride: 132%32=4 -> write conflicts 4-way->2-way; 132*4%16==0 keeps float4 align
#define GAP_TAU 0.0625f  // fp32 score gap below which we re-check in fp64
#define QGRID 1024       // k_quantize blocks (block-level loss reduction)

// ---- output offsets (d_out is float32, outputs concatenated in return order)
#define OUT_LOSS ((size_t)NROWS * DDIM)
#define OUT_IDX  (OUT_LOSS + 1)
#define OUT_MIND (OUT_IDX + NROWS)
#define OUT_PERP (OUT_MIND + NROWS)

// ---- workspace offsets (bytes); total needed ~6.8 MB
#define WS_SUM    0                              // double sum_sqerr
#define WS_NSUS   8                              // int n_suspect
#define WS_NVAL   12                             // unsigned n_valid
#define WS_COUNTS 256                            // float[KCODES]
#define WS_WSQ    (WS_COUNTS + 4*KCODES)         // float[KCODES]
#define WS_ROWS   (WS_WSQ + 4*KCODES)            // float[NROWS] row min score (dist - xsq)
#define WS_ROWI   (WS_ROWS + 4*NROWS)            // int[NROWS] row argmin
#define WS_SUSP   (WS_ROWI + 4*NROWS)            // int[NROWS] suspect rows
#define WS_PM1    (WS_SUSP + 4*NROWS)            // float[NROWS*NCB] partial min
#define WS_PM2    (WS_PM1 + (size_t)4*NROWS*NCB) // float[NROWS*NCB] partial 2nd min
#define WS_PIDX   (WS_PM2 + (size_t)4*NROWS*NCB) // int[NROWS*NCB] partial argmin
#define WS_END    (WS_PIDX + (size_t)4*NROWS*NCB)

template <typename T>
__device__ inline T waveRedAdd(T v) {
#pragma unroll
    for (int o = 32; o; o >>= 1) v += __shfl_xor(v, o);
    return v;
}

// ---------------------------------------------------------------- init
__global__ void k_init(float* counts, int* n_suspect, unsigned* n_valid, double* sum_sqerr) {
    const int t = threadIdx.x;
    if (t == 0) { *n_suspect = 0; *n_valid = 0u; *sum_sqerr = 0.0; }
    for (int k = t; k < KCODES; k += 256) counts[k] = 0.f;
}

// ---------------------------------------------------------------- ||e_k||^2
__global__ __launch_bounds__(256) void k_wsq(const float* __restrict__ W, float* __restrict__ wsq) {
    const int k = blockIdx.x;
    const int t = threadIdx.x;
    const float* w = W + (size_t)k * DDIM;
    const float a = w[t], b = w[t + 256], c = w[t + 512];
    float s = a * a + b * b + c * c;
    s = waveRedAdd(s);
    __shared__ float p[4];
    if ((t & 63) == 0) p[t >> 6] = s;
    __syncthreads();
    if (t == 0) wsq[k] = (p[0] + p[1]) + (p[2] + p[3]);
}

// ---------------------------------------------------------------- main GEMM + per-tile argmin
// score s_k = ||e_k||^2 - 2 x.e_k  (xsq added later; doesn't affect argmin)
// Block: 128 rows x 128 codes, D staged in double-buffered LDS chunks of 16
// (one barrier per chunk). Padded stride 132 -> LDS write conflicts 2-way (free).
__global__ __launch_bounds__(256, 4) void k_partials(
    const float* __restrict__ A, const float* __restrict__ W,
    const float* __restrict__ wsq,
    float* __restrict__ pm1, float* __restrict__ pm2, int* __restrict__ pidx)
{
    __shared__ __align__(16) float sm[2 * 2 * DC * LDST];   // [buf][A|W][16][132]

    const int rb = blockIdx.x, cb = blockIdx.y;
    const int tid = threadIdx.x;
    const int wid = tid >> 6, lane = tid & 63;
    const int lx = lane & 7, ly = lane >> 3;
    const int tx = ((wid & 1) << 3) | lx;   // 0..15 code-tile coord
    const int ty = ((wid >> 1) << 3) | ly;  // 0..15 row-tile coord

    const float* Ab = A + (size_t)rb * BM * DDIM;
    const float* Wb = W + (size_t)cb * BK * DDIM;

    const int sr = tid >> 2;         // 0..63 (row within staging)
    const int sd = (tid & 3) << 2;   // 0,4,8,12 (d within chunk)

    float acc[8][8];
#pragma unroll
    for (int r = 0; r < 8; ++r)
#pragma unroll
        for (int c = 0; c < 8; ++c) acc[r][c] = 0.f;

    float4 pa0, pa1, pw0, pw1;
    auto gload = [&](int ch) {
        const int d0 = ch * DC + sd;
        pa0 = *(const float4*)(Ab + (size_t)sr * DDIM + d0);
        pa1 = *(const float4*)(Ab + (size_t)(sr + 64) * DDIM + d0);
        pw0 = *(const float4*)(Wb + (size_t)sr * DDIM + d0);
        pw1 = *(const float4*)(Wb + (size_t)(sr + 64) * DDIM + d0);
    };
    auto lstore = [&](int b) {
        float* Al = sm + b * (2 * DC * LDST);
        float* Wl = Al + DC * LDST;
        Al[(sd + 0) * LDST + sr] = pa0.x; Al[(sd + 1) * LDST + sr] = pa0.y;
        Al[(sd + 2) * LDST + sr] = pa0.z; Al[(sd + 3) * LDST + sr] = pa0.w;
        Al[(sd + 0) * LDST + sr + 64] = pa1.x; Al[(sd + 1) * LDST + sr + 64] = pa1.y;
        Al[(sd + 2) * LDST + sr + 64] = pa1.z; Al[(sd + 3) * LDST + sr + 64] = pa1.w;
        Wl[(sd + 0) * LDST + sr] = pw0.x; Wl[(sd + 1) * LDST + sr] = pw0.y;
        Wl[(sd + 2) * LDST + sr] = pw0.z; Wl[(sd + 3) * LDST + sr] = pw0.w;
        Wl[(sd + 0) * LDST + sr + 64] = pw1.x; Wl[(sd + 1) * LDST + sr + 64] = pw1.y;
        Wl[(sd + 2) * LDST + sr + 64] = pw1.z; Wl[(sd + 3) * LDST + sr + 64] = pw1.w;
    };

    // prologue: stage chunk0 -> buf0, prefetch chunk1 into regs
    gload(0);
    lstore(0);
    gload(1);
    __syncthreads();

#pragma unroll 1
    for (int ch = 0; ch < NCH; ++ch) {
        const int cur = ch & 1;
        if (ch + 1 < NCH) lstore(cur ^ 1);   // regs hold chunk ch+1
        if (ch + 2 < NCH) gload(ch + 2);     // prefetch; latency hides under compute
        const float* Al = sm + cur * (2 * DC * LDST);
        const float* Wl = Al + DC * LDST;
#pragma unroll
        for (int d = 0; d < DC; ++d) {
            const float4 a0 = *(const float4*)(Al + d * LDST + ty * 8);
            const float4 a1 = *(const float4*)(Al + d * LDST + ty * 8 + 4);
            const float4 w0 = *(const float4*)(Wl + d * LDST + tx * 8);
            const float4 w1 = *(const float4*)(Wl + d * LDST + tx * 8 + 4);
            const float av[8] = {a0.x, a0.y, a0.z, a0.w, a1.x, a1.y, a1.z, a1.w};
            const float wv[8] = {w0.x, w0.y, w0.z, w0.w, w1.x, w1.y, w1.z, w1.w};
#pragma unroll
            for (int r = 0; r < 8; ++r)
#pragma unroll
                for (int c = 0; c < 8; ++c)
                    acc[r][c] = fmaf(av[r], wv[c], acc[r][c]);
        }
        __syncthreads();   // buf[cur^1] writes visible; buf[cur] reads done before overwrite
    }

    // ---------------- epilogue: per-row (min, 2nd-min, argmin) over this code tile
    float wsqv[8];
#pragma unroll
    for (int c = 0; c < 8; ++c) wsqv[c] = wsq[cb * BK + tx * 8 + c];

    float* tm1 = sm;                 // [128][2]
    float* tm2 = sm + 256;
    int*   ti1 = (int*)(sm + 512);

#pragma unroll
    for (int r = 0; r < 8; ++r) {
        float m1 = INFINITY, m2 = INFINITY; int i1 = 0x7fffffff;
#pragma unroll
        for (int c = 0; c < 8; ++c) {
            const float s = fmaf(-2.f, acc[r][c], wsqv[c]);
            const int k = cb * BK + tx * 8 + c;
            if (s < m1) { m2 = m1; m1 = s; i1 = k; }
            else if (s < m2) m2 = s;
        }
        // merge across lx (8 code-columns of this wave)
#pragma unroll
        for (int msk = 1; msk <= 4; msk <<= 1) {
            const float om1 = __shfl_xor(m1, msk);
            const float om2 = __shfl_xor(m2, msk);
            const int   oi1 = __shfl_xor(i1, msk);
            if (om1 < m1 || (om1 == m1 && oi1 < i1)) { m2 = fminf(m1, om2); m1 = om1; i1 = oi1; }
            else m2 = fminf(m2, om1);
        }
        if (lx == 0) {
            const int slot = (ty * 8 + r) * 2 + (wid & 1);
            tm1[slot] = m1; tm2[slot] = m2; ti1[slot] = i1;
        }
    }
    __syncthreads();
    if (tid < BM) {
        float m1 = tm1[tid * 2], m2 = tm2[tid * 2]; int i1 = ti1[tid * 2];
        const float bm1 = tm1[tid * 2 + 1], bm2 = tm2[tid * 2 + 1]; const int bi = ti1[tid * 2 + 1];
        if (bm1 < m1 || (bm1 == m1 && bi < i1)) { m2 = fminf(m1, bm2); m1 = bm1; i1 = bi; }
        else m2 = fminf(m2, bm1);
        const size_t row = (size_t)rb * BM + tid;
        pm1[row * NCB + cb] = m1;
        pm2[row * NCB + cb] = m2;
        pidx[row * NCB + cb] = i1;
    }
}

// ---------------------------------------------------------------- merge 8 partials per row
__global__ __launch_bounds__(256) void k_merge(
    const float* __restrict__ pm1, const float* __restrict__ pm2, const int* __restrict__ pidx,
    float* __restrict__ row_s, int* __restrict__ row_idx,
    int* __restrict__ suspects, int* __restrict__ n_suspect)
{
    const int row = blockIdx.x * 256 + threadIdx.x;
    float m1 = INFINITY, m2 = INFINITY; int i1 = 0x7fffffff;
#pragma unroll
    for (int cb = 0; cb < NCB; ++cb) {
        const float bm1 = pm1[(size_t)row * NCB + cb];
        const float bm2 = pm2[(size_t)row * NCB + cb];
        const int   bi  = pidx[(size_t)row * NCB + cb];
        if (bm1 < m1 || (bm1 == m1 && bi < i1)) { m2 = fminf(m1, bm2); m1 = bm1; i1 = bi; }
        else m2 = fminf(m2, bm1);
    }
    row_s[row] = m1;
    row_idx[row] = i1;
    if (m2 - m1 < GAP_TAU) {   // near-tie: fp32 argmin may differ from true argmin
        const int p = atomicAdd(n_suspect, 1);
        suspects[p] = row;
    }
}

// ---------------------------------------------------------------- fp64 re-check of near-ties
__global__ __launch_bounds__(256) void k_repair(
    const float* __restrict__ A, const float* __restrict__ W,
    const int* __restrict__ suspects, const int* __restrict__ n_suspect,
    float* __restrict__ row_s, int* __restrict__ row_idx)
{
    __shared__ float xrow[DDIM];
    __shared__ double wb[4]; __shared__ int wbi[4];
    __shared__ double sxsq;
    const int ns = *n_suspect;
    const int wid = threadIdx.x >> 6, lane = threadIdx.x & 63;
    for (int s = blockIdx.x; s < ns; s += gridDim.x) {
        const int row = suspects[s];
        __syncthreads();
        for (int i = threadIdx.x; i < DDIM; i += 256) xrow[i] = A[(size_t)row * DDIM + i];
        __syncthreads();
        if (wid == 0) {
            double xs = 0.0;
            for (int i = lane; i < DDIM; i += 64) { const double t = xrow[i]; xs += t * t; }
            xs = waveRedAdd(xs);
            if (lane == 0) sxsq = xs;
        }
        double best = 1e300; int bi = 0;
        const int k0 = wid * (KCODES / 4);
        for (int kk = 0; kk < KCODES / 4; ++kk) {
            const int k = k0 + kk;
            const float* wr = W + (size_t)k * DDIM;
            double d = 0.0;
            for (int i = lane; i < DDIM; i += 64) {
                const double t = (double)xrow[i] - (double)wr[i];
                d = fma(t, t, d);
            }
            d = waveRedAdd(d);
            if (d < best) { best = d; bi = k; }   // ascending k => first-index tiebreak
        }
        if (lane == 0) { wb[wid] = best; wbi[wid] = bi; }
        __syncthreads();
        if (threadIdx.x == 0) {
            double b = wb[0]; int i1 = wbi[0];
#pragma unroll
            for (int w = 1; w < 4; ++w) if (wb[w] < b) { b = wb[w]; i1 = wbi[w]; }
            row_idx[row] = i1;
            row_s[row] = (float)(b - sxsq);   // store score form (dist - xsq)
        }
    }
}

// ---------------------------------------------------------------- quantize + losses + idx/min_d outputs
// Block-level loss reduction: ONE double atomic + ONE uint atomic per block
// (was: one per wave -> 65536 same-address serialized atomics ~2ms).
__global__ __launch_bounds__(256) void k_quantize(
    const float* __restrict__ A, const float* __restrict__ W,
    const float* __restrict__ row_s, const int* __restrict__ row_idx,
    float* __restrict__ out, float* __restrict__ counts,
    unsigned int* __restrict__ n_valid, double* __restrict__ sum_sqerr)
{
    const int wid = threadIdx.x >> 6, lane = threadIdx.x & 63;
    __shared__ double s_sum[4];
    __shared__ unsigned s_val[4];
    double wsum = 0.0; unsigned wval = 0;

#pragma unroll 1
    for (int it = 0; it < NROWS / (QGRID * 4); ++it) {
        const int row = (it * QGRID + blockIdx.x) * 4 + wid;
        const float* x = A + (size_t)row * DDIM;
        float4 xv[3];
#pragma unroll
        for (int j = 0; j < 3; ++j) xv[j] = *(const float4*)(x + (lane + 64 * j) * 4);
        float xsq = 0.f;
#pragma unroll
        for (int j = 0; j < 3; ++j)
            xsq += xv[j].x * xv[j].x + xv[j].y * xv[j].y + xv[j].z * xv[j].z + xv[j].w * xv[j].w;
        xsq = waveRedAdd(xsq);
        const bool valid = xsq > 1e-12f;            // norm > 1e-6
        const float maskf = valid ? 1.f : 0.f;
        const int idx = row_idx[row];
        const int idxm = valid ? idx : 0;
        const float* w = W + (size_t)idx * DDIM;
        float* oq = out + (size_t)row * DDIM;
        float e2 = 0.f;
#pragma unroll
        for (int j = 0; j < 3; ++j) {
            const float4 wv = *(const float4*)(w + (lane + 64 * j) * 4);
            const float xs[4] = {xv[j].x, xv[j].y, xv[j].z, xv[j].w};
            const float ws[4] = {wv.x, wv.y, wv.z, wv.w};
            float os[4];
#pragma unroll
            for (int c = 0; c < 4; ++c) {
                const float q = ws[c] * maskf;          // q_flat = weight[idx] * mask
                os[c] = xs[c] + (q - xs[c]);            // quantized_st
                const float d = xs[c] - q;
                e2 += d * d;
            }
            float4 ov; ov.x = os[0]; ov.y = os[1]; ov.z = os[2]; ov.w = os[3];
            *(float4*)(oq + (lane + 64 * j) * 4) = ov;
        }
        e2 = waveRedAdd(e2);
        if (lane == 0) {
            wsum += (double)(maskf * e2);
            if (valid) {
                ++wval;
                atomicAdd(&counts[idxm], 1.0f);   // 1024 bins -> low contention
            }
            out[OUT_IDX + row]  = (float)idxm;
            out[OUT_MIND + row] = valid ? (xsq + row_s[row]) : 0.f;
        }
    }

    if (lane == 0) { s_sum[wid] = wsum; s_val[wid] = wval; }
    __syncthreads();
    if (threadIdx.x == 0) {
        atomicAdd(sum_sqerr, s_sum[0] + s_sum[1] + s_sum[2] + s_sum[3]);
        atomicAdd(n_valid, s_val[0] + s_val[1] + s_val[2] + s_val[3]);
    }
}

// ---------------------------------------------------------------- scalar losses
__global__ __launch_bounds__(256) void k_final(
    const float* __restrict__ counts, const unsigned int* __restrict__ n_valid,
    const double* __restrict__ sum_sqerr, float* __restrict__ out)
{
    const int t = threadIdx.x;
    const float nv = (float)(*n_valid);
    double ent = 0.0;
    for (int k = t; k < KCODES; k += 256) {
        const float p = counts[k] / nv;
        ent += (double)(p * logf(p + 1e-10f));
    }
    ent = waveRedAdd(ent);
    __shared__ double ps[4];
    if ((t & 63) == 0) ps[t >> 6] = ent;
    __syncthreads();
    if (t == 0) {
        const double e = ps[0] + ps[1] + ps[2] + ps[3];
        const double perp = exp(-e);
        const double ploss = -log(perp + 1e-10);
        const double commit = *sum_sqerr / ((double)(*n_valid) * (double)DDIM);
        out[OUT_LOSS] = (float)(0.25 * commit + 0.1 * ploss);
        out[OUT_PERP] = (float)perp;
    }
}

// ----------------------------------------------------------------
extern "C" void kernel_launch(void* const* d_in, const int* in_sizes, int n_in,
                              void* d_out, int out_size, void* d_ws, size_t ws_size,
                              hipStream_t stream) {
    const float* A = (const float*)d_in[0];   // [65536, 768]
    const float* W = (const float*)d_in[1];   // [1024, 768]
    float* out = (float*)d_out;
    char* ws = (char*)d_ws;
    if (ws_size < (size_t)WS_END) return;     // needs ~6.8 MB scratch

    double*   sum_sqerr = (double*)(ws + WS_SUM);
    int*      n_suspect = (int*)(ws + WS_NSUS);
    unsigned* n_valid   = (unsigned*)(ws + WS_NVAL);
    float*    counts    = (float*)(ws + WS_COUNTS);
    float*    wsq       = (float*)(ws + WS_WSQ);
    float*    row_s     = (float*)(ws + WS_ROWS);
    int*      row_idx   = (int*)(ws + WS_ROWI);
    int*      suspects  = (int*)(ws + WS_SUSP);
    float*    pm1       = (float*)(ws + WS_PM1);
    float*    pm2       = (float*)(ws + WS_PM2);
    int*      pidx      = (int*)(ws + WS_PIDX);

    hipLaunchKernelGGL(k_init, dim3(1), dim3(256), 0, stream, counts, n_suspect, n_valid, sum_sqerr);
    hipLaunchKernelGGL(k_wsq, dim3(KCODES), dim3(256), 0, stream, W, wsq);
    hipLaunchKernelGGL(k_partials, dim3(NROWS / BM, NCB), dim3(256), 0, stream, A, W, wsq, pm1, pm2, pidx);
    hipLaunchKernelGGL(k_merge, dim3(NROWS / 256), dim3(256), 0, stream, pm1, pm2, pidx, row_s, row_idx, suspects, n_suspect);
    hipLaunchKernelGGL(k_repair, dim3(256), dim3(256), 0, stream, A, W, suspects, n_suspect, row_s, row_idx);
    hipLaunchKernelGGL(k_quantize, dim3(QGRID), dim3(256), 0, stream, A, W, row_s, row_idx, out, counts, n_valid, sum_sqerr);
    hipLaunchKernelGGL(k_final, dim3(1), dim3(256), 0, stream, counts, n_valid, sum_sqerr, out);
}

// Round 4
// 5365.965 us; speedup vs baseline: 1.2436x; 1.2436x over previous
//
#include <hip/hip_runtime.h>
#include <hip/hip_bf16.h>
#include <math.h>

// Problem constants
#define NROWS 65536      // 32*2048
#define DDIM  768
#define KCODES 1024
#define NCB   8          // code blocks (KCODES / BK)
#define BM    128        // rows per block tile
#define BK    128        // codes per block tile
#define KC    32         // K-chunk (one mfma_16x16x32 pass)
#define NCH   (DDIM / KC)
#define GAP_TAU 1.0f     // bf16 score-error guard band (~8 sigma); near-ties re-checked in fp64

// ---- output offsets (d_out is float32, outputs concatenated in return order)
#define OUT_LOSS ((size_t)NROWS * DDIM)
#define OUT_IDX  (OUT_LOSS + 1)
#define OUT_MIND (OUT_IDX + NROWS)
#define OUT_PERP (OUT_MIND + NROWS)

// ---- workspace offsets (bytes); total ~6.8 MB
#define WS_SUM    0                              // double sum_sqerr
#define WS_NSUS   8                              // int n_suspect
#define WS_NVAL   12                              // unsigned n_valid
#define WS_COUNTS 256                            // float[KCODES]
#define WS_WSQ    (WS_COUNTS + 4*KCODES)         // float[KCODES]
#define WS_ROWS   (WS_WSQ + 4*KCODES)            // float[NROWS] row min score (dist - xsq)
#define WS_ROWI   (WS_ROWS + 4*NROWS)            // int[NROWS] row argmin
#define WS_SUSP   (WS_ROWI + 4*NROWS)            // int[NROWS] suspect rows
#define WS_PM1    (WS_SUSP + 4*NROWS)            // float[NROWS*NCB] partial min
#define WS_PM2    (WS_PM1 + (size_t)4*NROWS*NCB) // float[NROWS*NCB] partial 2nd min
#define WS_PIDX   (WS_PM2 + (size_t)4*NROWS*NCB) // int[NROWS*NCB] partial argmin
#define WS_END    (WS_PIDX + (size_t)4*NROWS*NCB)

#define QGRID 1024       // k_quantize blocks

typedef __attribute__((ext_vector_type(8))) short short8;   // 8 bf16 = 4 VGPRs (MFMA A/B frag)
typedef __attribute__((ext_vector_type(4))) float f32x4;    // MFMA C/D frag

template <typename T>
__device__ inline T waveRedAdd(T v) {
#pragma unroll
    for (int o = 32; o; o >>= 1) v += __shfl_xor(v, o);
    return v;
}

__device__ inline ushort f2bf(float f) {
    union { __hip_bfloat16 h; ushort u; } c;
    c.h = __float2bfloat16(f);   // RTN-even; compiler pairs into v_cvt_pk_bf16_f32
    return c.u;
}

// ---------------------------------------------------------------- init
__global__ void k_init(float* counts, int* n_suspect, unsigned* n_valid, double* sum_sqerr) {
    const int t = threadIdx.x;
    if (t == 0) { *n_suspect = 0; *n_valid = 0u; *sum_sqerr = 0.0; }
    for (int k = t; k < KCODES; k += 256) counts[k] = 0.f;
}

// ---------------------------------------------------------------- ||e_k||^2 (exact fp32)
__global__ __launch_bounds__(256) void k_wsq(const float* __restrict__ W, float* __restrict__ wsq) {
    const int k = blockIdx.x;
    const int t = threadIdx.x;
    const float* w = W + (size_t)k * DDIM;
    const float a = w[t], b = w[t + 256], c = w[t + 512];
    float s = a * a + b * b + c * c;
    s = waveRedAdd(s);
    __shared__ float p[4];
    if ((t & 63) == 0) p[t >> 6] = s;
    __syncthreads();
    if (t == 0) wsq[k] = (p[0] + p[1]) + (p[2] + p[3]);
}

// ---------------------------------------------------------------- main GEMM (bf16 MFMA) + per-tile argmin
// score s_k = ||e_k||^2 - 2 x.e_k  (xsq added later; doesn't affect argmin).
// 128x128 tile, 4 waves (2x2 quadrants of 64x64), K staged in LDS chunks of 32 bf16.
// Each wave reduces its 64-col half per row; the two column-halves are then merged
// through LDS before writing pm* (round-3 bug: both halves raced on the same slot).
__global__ __launch_bounds__(256, 2) void k_partials(
    const float* __restrict__ A, const float* __restrict__ W,
    const float* __restrict__ wsq,
    float* __restrict__ pm1, float* __restrict__ pm2, int* __restrict__ pidx)
{
    __shared__ __align__(16) ushort lds[2 * BM * KC];   // As[128][32] | Ws[128][32] bf16
    ushort* As = lds;
    ushort* Ws = lds + BM * KC;

    // XCD-panel swizzle: consecutive blockIdx round-robin XCDs (bid&7); each XCD owns
    // a contiguous band of 64 row-panels, code-block fastest -> A HBM-fetched once.
    const int bid = blockIdx.x;
    const int rb = ((bid & 7) << 6) | (bid >> 6);
    const int cb = (bid >> 3) & 7;

    const int tid = threadIdx.x;
    const int wid = tid >> 6, lane = tid & 63;
    const int wr = wid >> 1, wc = wid & 1;       // wave quadrant (row-half, col-half)
    const int l15 = lane & 15, g = lane >> 4;    // frag row/col + k-group

    const float* Ab = A + (size_t)rb * BM * DDIM;
    const float* Wb = W + (size_t)cb * BK * DDIM;

    // staging map: thread t loads rows (t>>3)+32i, fp32 k-quad (t&7)*4 of the chunk
    const int srow = tid >> 3;            // 0..31
    const int sk4  = (tid & 7) << 2;      // 0..28
    const int sg   = (tid & 7) >> 1;      // 16B slot 0..3
    const int sh   = (tid & 1) << 2;      // half-slot (ushort offset 0 or 4)

    // fragment LDS offsets (ushort units), loop-invariant; slot swizzle s = g ^ ((r>>1)&3)
    int aOff[4], bOff[4];
#pragma unroll
    for (int rt = 0; rt < 4; ++rt) {
        const int r = wr * 64 + rt * 16 + l15;
        aOff[rt] = r * KC + ((g ^ ((r >> 1) & 3)) << 3);
        const int c = wc * 64 + rt * 16 + l15;
        bOff[rt] = c * KC + ((g ^ ((c >> 1) & 3)) << 3);
    }

    f32x4 acc[4][4];
#pragma unroll
    for (int rt = 0; rt < 4; ++rt)
#pragma unroll
        for (int ct = 0; ct < 4; ++ct) acc[rt][ct] = (f32x4)0.f;

    float4 av[4], wv[4];
#pragma unroll
    for (int i = 0; i < 4; ++i) {   // prologue: chunk 0
        av[i] = *(const float4*)(Ab + (size_t)(srow + 32 * i) * DDIM + sk4);
        wv[i] = *(const float4*)(Wb + (size_t)(srow + 32 * i) * DDIM + sk4);
    }

#pragma unroll 1
    for (int ch = 0; ch < NCH; ++ch) {
        __syncthreads();   // previous compute done reading LDS
#pragma unroll
        for (int i = 0; i < 4; ++i) {
            const int r = srow + 32 * i;
            const int wsl = r * KC + ((sg ^ ((r >> 1) & 3)) << 3) + sh;
            ushort4 ua; ua.x = f2bf(av[i].x); ua.y = f2bf(av[i].y); ua.z = f2bf(av[i].z); ua.w = f2bf(av[i].w);
            *(ushort4*)(As + wsl) = ua;
            ushort4 uw; uw.x = f2bf(wv[i].x); uw.y = f2bf(wv[i].y); uw.z = f2bf(wv[i].z); uw.w = f2bf(wv[i].w);
            *(ushort4*)(Ws + wsl) = uw;
        }
        __syncthreads();   // LDS ready
        if (ch + 1 < NCH) {
            const int d0 = (ch + 1) * KC + sk4;
#pragma unroll
            for (int i = 0; i < 4; ++i) {
                av[i] = *(const float4*)(Ab + (size_t)(srow + 32 * i) * DDIM + d0);
                wv[i] = *(const float4*)(Wb + (size_t)(srow + 32 * i) * DDIM + d0);
            }
        }
        short8 af[4], bf[4];
#pragma unroll
        for (int rt = 0; rt < 4; ++rt) af[rt] = *(const short8*)(As + aOff[rt]);
#pragma unroll
        for (int ct = 0; ct < 4; ++ct) bf[ct] = *(const short8*)(Ws + bOff[ct]);
#pragma unroll
        for (int rt = 0; rt < 4; ++rt)
#pragma unroll
            for (int ct = 0; ct < 4; ++ct)
                acc[rt][ct] = __builtin_amdgcn_mfma_f32_16x16x32_bf16(af[rt], bf[ct], acc[rt][ct], 0, 0, 0);
    }

    // ---------------- epilogue: per-row (min, 2nd-min, argmin) over this 128-code tile
    // C/D layout: col = lane&15, row = (lane>>4)*4 + q  [m89]
    float wq[4];
#pragma unroll
    for (int ct = 0; ct < 4; ++ct) wq[ct] = wsq[cb * BK + wc * 64 + ct * 16 + l15];
    const int cbase = cb * BK + wc * 64 + l15;

    __syncthreads();   // staging reads drained; reuse LDS for the column-half merge
    float* tm1 = (float*)lds;          // [128][2]  (row-local, wc)
    float* tm2 = tm1 + 256;
    int*   ti1 = (int*)(tm2 + 256);

#pragma unroll
    for (int rt = 0; rt < 4; ++rt) {
        float m1q[4], m2q[4]; int i1q[4];
#pragma unroll
        for (int q = 0; q < 4; ++q) { m1q[q] = INFINITY; m2q[q] = INFINITY; i1q[q] = 0x7fffffff; }
#pragma unroll
        for (int ct = 0; ct < 4; ++ct) {
            const int col = cbase + ct * 16;
#pragma unroll
            for (int q = 0; q < 4; ++q) {
                const float s = fmaf(-2.f, acc[rt][ct][q], wq[ct]);
                if (s < m1q[q]) { m2q[q] = m1q[q]; m1q[q] = s; i1q[q] = col; }
                else if (s < m2q[q]) m2q[q] = s;
            }
        }
        // reduce across the 16 lanes of the row group (l15 dimension)
#pragma unroll
        for (int msk = 1; msk <= 8; msk <<= 1) {
#pragma unroll
            for (int q = 0; q < 4; ++q) {
                const float om1 = __shfl_xor(m1q[q], msk);
                const float om2 = __shfl_xor(m2q[q], msk);
                const int   oi1 = __shfl_xor(i1q[q], msk);
                if (om1 < m1q[q] || (om1 == m1q[q] && oi1 < i1q[q])) {
                    m2q[q] = fminf(m1q[q], om2); m1q[q] = om1; i1q[q] = oi1;
                } else m2q[q] = fminf(m2q[q], om1);
            }
        }
        if (l15 == 0) {
#pragma unroll
            for (int q = 0; q < 4; ++q) {
                const int rl = wr * 64 + rt * 16 + g * 4 + q;   // row within block
                tm1[rl * 2 + wc] = m1q[q];
                tm2[rl * 2 + wc] = m2q[q];
                ti1[rl * 2 + wc] = i1q[q];
            }
        }
    }
    __syncthreads();
    if (tid < BM) {
        float m1 = tm1[tid * 2], m2 = tm2[tid * 2]; int i1 = ti1[tid * 2];
        const float bm1 = tm1[tid * 2 + 1], bm2 = tm2[tid * 2 + 1]; const int bi = ti1[tid * 2 + 1];
        if (bm1 < m1 || (bm1 == m1 && bi < i1)) { m2 = fminf(m1, bm2); m1 = bm1; i1 = bi; }
        else m2 = fminf(m2, bm1);
        const size_t row = (size_t)rb * BM + tid;
        pm1[row * NCB + cb] = m1;
        pm2[row * NCB + cb] = m2;
        pidx[row * NCB + cb] = i1;
    }
}

// ---------------------------------------------------------------- merge 8 partials per row
__global__ __launch_bounds__(256) void k_merge(
    const float* __restrict__ pm1, const float* __restrict__ pm2, const int* __restrict__ pidx,
    float* __restrict__ row_s, int* __restrict__ row_idx,
    int* __restrict__ suspects, int* __restrict__ n_suspect)
{
    const int row = blockIdx.x * 256 + threadIdx.x;
    float m1 = INFINITY, m2 = INFINITY; int i1 = 0x7fffffff;
#pragma unroll
    for (int cb = 0; cb < NCB; ++cb) {
        const float bm1 = pm1[(size_t)row * NCB + cb];
        const float bm2 = pm2[(size_t)row * NCB + cb];
        const int   bi  = pidx[(size_t)row * NCB + cb];
        if (bm1 < m1 || (bm1 == m1 && bi < i1)) { m2 = fminf(m1, bm2); m1 = bm1; i1 = bi; }
        else m2 = fminf(m2, bm1);
    }
    row_s[row] = m1;
    row_idx[row] = i1;
    if (m2 - m1 < GAP_TAU) {   // bf16 noise could have reordered: exact re-check
        const int p = atomicAdd(n_suspect, 1);
        suspects[p] = row;
    }
}

// ---------------------------------------------------------------- fp64 re-check of near-ties
__global__ __launch_bounds__(256) void k_repair(
    const float* __restrict__ A, const float* __restrict__ W,
    const int* __restrict__ suspects, const int* __restrict__ n_suspect,
    float* __restrict__ row_s, int* __restrict__ row_idx)
{
    __shared__ float xrow[DDIM];
    __shared__ double wb[4]; __shared__ int wbi[4];
    __shared__ double sxsq;
    const int ns = *n_suspect;
    const int wid = threadIdx.x >> 6, lane = threadIdx.x & 63;
    for (int s = blockIdx.x; s < ns; s += gridDim.x) {
        const int row = suspects[s];
        __syncthreads();
        for (int i = threadIdx.x; i < DDIM; i += 256) xrow[i] = A[(size_t)row * DDIM + i];
        __syncthreads();
        if (wid == 0) {
            double xs = 0.0;
            for (int i = lane; i < DDIM; i += 64) { const double t = xrow[i]; xs += t * t; }
            xs = waveRedAdd(xs);
            if (lane == 0) sxsq = xs;
        }
        double best = 1e300; int bi = 0;
        const int k0 = wid * (KCODES / 4);
        for (int kk = 0; kk < KCODES / 4; ++kk) {
            const int k = k0 + kk;
            const float* wr = W + (size_t)k * DDIM;
            double d = 0.0;
            for (int i = lane; i < DDIM; i += 64) {
                const double t = (double)xrow[i] - (double)wr[i];
                d = fma(t, t, d);
            }
            d = waveRedAdd(d);
            if (d < best) { best = d; bi = k; }   // ascending k => first-index tiebreak
        }
        if (lane == 0) { wb[wid] = best; wbi[wid] = bi; }
        __syncthreads();
        if (threadIdx.x == 0) {
            double b = wb[0]; int i1 = wbi[0];
#pragma unroll
            for (int w = 1; w < 4; ++w) if (wb[w] < b) { b = wb[w]; i1 = wbi[w]; }
            row_idx[row] = i1;
            row_s[row] = (float)(b - sxsq);   // store score form (dist - xsq)
        }
        __syncthreads();
    }
}

// ---------------------------------------------------------------- quantize + losses + idx/min_d outputs
__global__ __launch_bounds__(256) void k_quantize(
    const float* __restrict__ A, const float* __restrict__ W,
    const float* __restrict__ row_s, const int* __restrict__ row_idx,
    float* __restrict__ out, float* __restrict__ counts,
    unsigned int* __restrict__ n_valid, double* __restrict__ sum_sqerr)
{
    const int wid = threadIdx.x >> 6, lane = threadIdx.x & 63;
    __shared__ double s_sum[4];
    __shared__ unsigned s_val[4];
    double wsum = 0.0; unsigned wval = 0;

#pragma unroll 1
    for (int it = 0; it < NROWS / (QGRID * 4); ++it) {
        const int row = (it * QGRID + blockIdx.x) * 4 + wid;
        const float* x = A + (size_t)row * DDIM;
        float4 xv[3];
#pragma unroll
        for (int j = 0; j < 3; ++j) xv[j] = *(const float4*)(x + (lane + 64 * j) * 4);
        float xsq = 0.f;
#pragma unroll
        for (int j = 0; j < 3; ++j)
            xsq += xv[j].x * xv[j].x + xv[j].y * xv[j].y + xv[j].z * xv[j].z + xv[j].w * xv[j].w;
        xsq = waveRedAdd(xsq);
        const bool valid = xsq > 1e-12f;            // norm > 1e-6
        const float maskf = valid ? 1.f : 0.f;
        const int idx = row_idx[row];
        const int idxm = valid ? idx : 0;
        const float* w = W + (size_t)idx * DDIM;
        float* oq = out + (size_t)row * DDIM;
        float e2 = 0.f;
#pragma unroll
        for (int j = 0; j < 3; ++j) {
            const float4 wvv = *(const float4*)(w + (lane + 64 * j) * 4);
            const float xs[4] = {xv[j].x, xv[j].y, xv[j].z, xv[j].w};
            const float ws[4] = {wvv.x, wvv.y, wvv.z, wvv.w};
            float os[4];
#pragma unroll
            for (int c = 0; c < 4; ++c) {
                const float q = ws[c] * maskf;          // q_flat = weight[idx] * mask
                os[c] = xs[c] + (q - xs[c]);            // quantized_st
                const float d = xs[c] - q;
                e2 += d * d;
            }
            float4 ov; ov.x = os[0]; ov.y = os[1]; ov.z = os[2]; ov.w = os[3];
            *(float4*)(oq + (lane + 64 * j) * 4) = ov;
        }
        e2 = waveRedAdd(e2);
        if (lane == 0) {
            wsum += (double)(maskf * e2);
            if (valid) {
                ++wval;
                atomicAdd(&counts[idxm], 1.0f);   // 1024 bins -> low contention
            }
            out[OUT_IDX + row]  = (float)idxm;
            out[OUT_MIND + row] = valid ? (xsq + row_s[row]) : 0.f;
        }
    }

    if (lane == 0) { s_sum[wid] = wsum; s_val[wid] = wval; }
    __syncthreads();
    if (threadIdx.x == 0) {
        atomicAdd(sum_sqerr, s_sum[0] + s_sum[1] + s_sum[2] + s_sum[3]);
        atomicAdd(n_valid, s_val[0] + s_val[1] + s_val[2] + s_val[3]);
    }
}

// ---------------------------------------------------------------- scalar losses
__global__ __launch_bounds__(256) void k_final(
    const float* __restrict__ counts, const unsigned int* __restrict__ n_valid,
    const double* __restrict__ sum_sqerr, float* __restrict__ out)
{
    const int t = threadIdx.x;
    const float nv = (float)(*n_valid);
    double ent = 0.0;
    for (int k = t; k < KCODES; k += 256) {
        const float p = counts[k] / nv;
        ent += (double)(p * logf(p + 1e-10f));
    }
    ent = waveRedAdd(ent);
    __shared__ double ps[4];
    if ((t & 63) == 0) ps[t >> 6] = ent;
    __syncthreads();
    if (t == 0) {
        const double e = ps[0] + ps[1] + ps[2] + ps[3];
        const double perp = exp(-e);
        const double ploss = -log(perp + 1e-10);
        const double commit = *sum_sqerr / ((double)(*n_valid) * (double)DDIM);
        out[OUT_LOSS] = (float)(0.25 * commit + 0.1 * ploss);
        out[OUT_PERP] = (float)perp;
    }
}

// ----------------------------------------------------------------
extern "C" void kernel_launch(void* const* d_in, const int* in_sizes, int n_in,
                              void* d_out, int out_size, void* d_ws, size_t ws_size,
                              hipStream_t stream) {
    const float* A = (const float*)d_in[0];   // [65536, 768]
    const float* W = (const float*)d_in[1];   // [1024, 768]
    float* out = (float*)d_out;
    char* ws = (char*)d_ws;
    if (ws_size < (size_t)WS_END) return;     // needs ~6.8 MB scratch

    double*   sum_sqerr = (double*)(ws + WS_SUM);
    int*      n_suspect = (int*)(ws + WS_NSUS);
    unsigned* n_valid   = (unsigned*)(ws + WS_NVAL);
    float*    counts    = (float*)(ws + WS_COUNTS);
    float*    wsq       = (float*)(ws + WS_WSQ);
    float*    row_s     = (float*)(ws + WS_ROWS);
    int*      row_idx   = (int*)(ws + WS_ROWI);
    int*      suspects  = (int*)(ws + WS_SUSP);
    float*    pm1       = (float*)(ws + WS_PM1);
    float*    pm2       = (float*)(ws + WS_PM2);
    int*      pidx      = (int*)(ws + WS_PIDX);

    hipLaunchKernelGGL(k_init, dim3(1), dim3(256), 0, stream, counts, n_suspect, n_valid, sum_sqerr);
    hipLaunchKernelGGL(k_wsq, dim3(KCODES), dim3(256), 0, stream, W, wsq);
    hipLaunchKernelGGL(k_partials, dim3((NROWS / BM) * NCB), dim3(256), 0, stream, A, W, wsq, pm1, pm2, pidx);
    hipLaunchKernelGGL(k_merge, dim3(NROWS / 256), dim3(256), 0, stream, pm1, pm2, pidx, row_s, row_idx, suspects, n_suspect);
    hipLaunchKernelGGL(k_repair, dim3(256), dim3(256), 0, stream, A, W, suspects, n_suspect, row_s, row_idx);
    hipLaunchKernelGGL(k_quantize, dim3(QGRID), dim3(256), 0, stream, A, W, row_s, row_idx, out, counts, n_valid, sum_sqerr);
    hipLaunchKernelGGL(k_final, dim3(1), dim3(256), 0, stream, counts, n_valid, sum_sqerr, out);
}

// Round 5
// 499.303 us; speedup vs baseline: 13.3645x; 10.7469x over previous
//
#include <hip/hip_runtime.h>
#include <hip/hip_bf16.h>
#include <math.h>

// Problem constants
#define NROWS 65536      // 32*2048
#define DDIM  768
#define KCODES 1024
#define NCB   8          // code blocks (KCODES / BK)
#define BM    128        // rows per block tile
#define BK    128        // codes per block tile
#define KC    32         // K-chunk (one mfma_16x16x32 pass)
#define NCH   (DDIM / KC)
#define GAP_TAU  0.4f    // fp16 score-error guard band (~18 sigma); near-ties re-checked in fp64
#define FILT_TAU 0.8f    // repair block-filter margin (2x guard band)
#define RGRID 512        // k_repair blocks

// ---- output offsets (d_out is float32, outputs concatenated in return order)
#define OUT_LOSS ((size_t)NROWS * DDIM)
#define OUT_IDX  (OUT_LOSS + 1)
#define OUT_MIND (OUT_IDX + NROWS)
#define OUT_PERP (OUT_MIND + NROWS)

// ---- workspace offsets (bytes); total ~6.8 MB
#define WS_SUM    0                              // double sum_sqerr
#define WS_NSUS   8                              // int n_suspect
#define WS_NVAL   12                             // unsigned n_valid
#define WS_COUNTS 256                            // float[KCODES]
#define WS_WSQ    (WS_COUNTS + 4*KCODES)         // float[KCODES]
#define WS_ROWS   (WS_WSQ + 4*KCODES)            // float[NROWS] row min score (dist - xsq)
#define WS_ROWI   (WS_ROWS + 4*NROWS)            // int[NROWS] row argmin
#define WS_SUSP   (WS_ROWI + 4*NROWS)            // int[NROWS] suspect rows
#define WS_PM1    (WS_SUSP + 4*NROWS)            // float[NROWS*NCB] partial min
#define WS_PM2    (WS_PM1 + (size_t)4*NROWS*NCB) // float[NROWS*NCB] partial 2nd min
#define WS_PIDX   (WS_PM2 + (size_t)4*NROWS*NCB) // int[NROWS*NCB] partial argmin
#define WS_END    (WS_PIDX + (size_t)4*NROWS*NCB)

#define QGRID 1024       // k_quantize blocks

typedef __attribute__((ext_vector_type(8))) _Float16 half8;  // 8 f16 = 4 VGPRs (MFMA A/B frag)
typedef __attribute__((ext_vector_type(4))) float f32x4;     // MFMA C/D frag

template <typename T>
__device__ inline T waveRedAdd(T v) {
#pragma unroll
    for (int o = 32; o; o >>= 1) v += __shfl_xor(v, o);
    return v;
}

__device__ inline ushort f2h(float f) {
    union { _Float16 h; ushort u; } c;
    c.h = (_Float16)f;   // RTN-even; pairs into v_cvt_f16_f32
    return c.u;
}

// ---------------------------------------------------------------- init
__global__ void k_init(float* counts, int* n_suspect, unsigned* n_valid, double* sum_sqerr) {
    const int t = threadIdx.x;
    if (t == 0) { *n_suspect = 0; *n_valid = 0u; *sum_sqerr = 0.0; }
    for (int k = t; k < KCODES; k += 256) counts[k] = 0.f;
}

// ---------------------------------------------------------------- ||e_k||^2 (exact fp32)
__global__ __launch_bounds__(256) void k_wsq(const float* __restrict__ W, float* __restrict__ wsq) {
    const int k = blockIdx.x;
    const int t = threadIdx.x;
    const float* w = W + (size_t)k * DDIM;
    const float a = w[t], b = w[t + 256], c = w[t + 512];
    float s = a * a + b * b + c * c;
    s = waveRedAdd(s);
    __shared__ float p[4];
    if ((t & 63) == 0) p[t >> 6] = s;
    __syncthreads();
    if (t == 0) wsq[k] = (p[0] + p[1]) + (p[2] + p[3]);
}

// ---------------------------------------------------------------- main GEMM (fp16 MFMA) + per-tile argmin
// score s_k = ||e_k||^2 - 2 x.e_k  (xsq added later; doesn't affect argmin).
// 128x128 tile, 4 waves (2x2 quadrants of 64x64), K staged in LDS chunks of 32 fp16.
// Column-halves merged through LDS before writing pm* (round-3 race fixed in r4).
__global__ __launch_bounds__(256, 2) void k_partials(
    const float* __restrict__ A, const float* __restrict__ W,
    const float* __restrict__ wsq,
    float* __restrict__ pm1, float* __restrict__ pm2, int* __restrict__ pidx)
{
    __shared__ __align__(16) ushort lds[2 * BM * KC];   // As[128][32] | Ws[128][32] fp16
    ushort* As = lds;
    ushort* Ws = lds + BM * KC;

    // XCD-panel swizzle: consecutive blockIdx round-robin XCDs (bid&7); each XCD owns
    // a contiguous band of 64 row-panels, code-block fastest -> A HBM-fetched once.
    const int bid = blockIdx.x;
    const int rb = ((bid & 7) << 6) | (bid >> 6);
    const int cb = (bid >> 3) & 7;

    const int tid = threadIdx.x;
    const int wid = tid >> 6, lane = tid & 63;
    const int wr = wid >> 1, wc = wid & 1;       // wave quadrant (row-half, col-half)
    const int l15 = lane & 15, g = lane >> 4;    // frag row/col + k-group

    const float* Ab = A + (size_t)rb * BM * DDIM;
    const float* Wb = W + (size_t)cb * BK * DDIM;

    // staging map: thread t loads rows (t>>3)+32i, fp32 k-quad (t&7)*4 of the chunk
    const int srow = tid >> 3;            // 0..31
    const int sk4  = (tid & 7) << 2;      // 0..28
    const int sg   = (tid & 7) >> 1;      // 16B slot 0..3
    const int sh   = (tid & 1) << 2;      // half-slot (ushort offset 0 or 4)

    // fragment LDS offsets (ushort units), loop-invariant; slot swizzle s = g ^ ((r>>1)&3)
    int aOff[4], bOff[4];
#pragma unroll
    for (int rt = 0; rt < 4; ++rt) {
        const int r = wr * 64 + rt * 16 + l15;
        aOff[rt] = r * KC + ((g ^ ((r >> 1) & 3)) << 3);
        const int c = wc * 64 + rt * 16 + l15;
        bOff[rt] = c * KC + ((g ^ ((c >> 1) & 3)) << 3);
    }

    f32x4 acc[4][4];
#pragma unroll
    for (int rt = 0; rt < 4; ++rt)
#pragma unroll
        for (int ct = 0; ct < 4; ++ct) acc[rt][ct] = (f32x4)0.f;

    float4 av[4], wv[4];
#pragma unroll
    for (int i = 0; i < 4; ++i) {   // prologue: chunk 0
        av[i] = *(const float4*)(Ab + (size_t)(srow + 32 * i) * DDIM + sk4);
        wv[i] = *(const float4*)(Wb + (size_t)(srow + 32 * i) * DDIM + sk4);
    }

#pragma unroll 1
    for (int ch = 0; ch < NCH; ++ch) {
        __syncthreads();   // previous compute done reading LDS
#pragma unroll
        for (int i = 0; i < 4; ++i) {
            const int r = srow + 32 * i;
            const int wsl = r * KC + ((sg ^ ((r >> 1) & 3)) << 3) + sh;
            ushort4 ua; ua.x = f2h(av[i].x); ua.y = f2h(av[i].y); ua.z = f2h(av[i].z); ua.w = f2h(av[i].w);
            *(ushort4*)(As + wsl) = ua;
            ushort4 uw; uw.x = f2h(wv[i].x); uw.y = f2h(wv[i].y); uw.z = f2h(wv[i].z); uw.w = f2h(wv[i].w);
            *(ushort4*)(Ws + wsl) = uw;
        }
        __syncthreads();   // LDS ready
        if (ch + 1 < NCH) {
            const int d0 = (ch + 1) * KC + sk4;
#pragma unroll
            for (int i = 0; i < 4; ++i) {
                av[i] = *(const float4*)(Ab + (size_t)(srow + 32 * i) * DDIM + d0);
                wv[i] = *(const float4*)(Wb + (size_t)(srow + 32 * i) * DDIM + d0);
            }
        }
        half8 af[4], bf[4];
#pragma unroll
        for (int rt = 0; rt < 4; ++rt) af[rt] = *(const half8*)(As + aOff[rt]);
#pragma unroll
        for (int ct = 0; ct < 4; ++ct) bf[ct] = *(const half8*)(Ws + bOff[ct]);
#pragma unroll
        for (int rt = 0; rt < 4; ++rt)
#pragma unroll
            for (int ct = 0; ct < 4; ++ct)
                acc[rt][ct] = __builtin_amdgcn_mfma_f32_16x16x32_f16(af[rt], bf[ct], acc[rt][ct], 0, 0, 0);
    }

    // ---------------- epilogue: per-row (min, 2nd-min, argmin) over this 128-code tile
    // C/D layout: col = lane&15, row = (lane>>4)*4 + q  [m89]
    float wq[4];
#pragma unroll
    for (int ct = 0; ct < 4; ++ct) wq[ct] = wsq[cb * BK + wc * 64 + ct * 16 + l15];
    const int cbase = cb * BK + wc * 64 + l15;

    __syncthreads();   // staging reads drained; reuse LDS for the column-half merge
    float* tm1 = (float*)lds;          // [128][2]  (row-local, wc)
    float* tm2 = tm1 + 256;
    int*   ti1 = (int*)(tm2 + 256);

#pragma unroll
    for (int rt = 0; rt < 4; ++rt) {
        float m1q[4], m2q[4]; int i1q[4];
#pragma unroll
        for (int q = 0; q < 4; ++q) { m1q[q] = INFINITY; m2q[q] = INFINITY; i1q[q] = 0x7fffffff; }
#pragma unroll
        for (int ct = 0; ct < 4; ++ct) {
            const int col = cbase + ct * 16;
#pragma unroll
            for (int q = 0; q < 4; ++q) {
                const float s = fmaf(-2.f, acc[rt][ct][q], wq[ct]);
                if (s < m1q[q]) { m2q[q] = m1q[q]; m1q[q] = s; i1q[q] = col; }
                else if (s < m2q[q]) m2q[q] = s;
            }
        }
        // reduce across the 16 lanes of the row group (l15 dimension)
#pragma unroll
        for (int msk = 1; msk <= 8; msk <<= 1) {
#pragma unroll
            for (int q = 0; q < 4; ++q) {
                const float om1 = __shfl_xor(m1q[q], msk);
                const float om2 = __shfl_xor(m2q[q], msk);
                const int   oi1 = __shfl_xor(i1q[q], msk);
                if (om1 < m1q[q] || (om1 == m1q[q] && oi1 < i1q[q])) {
                    m2q[q] = fminf(m1q[q], om2); m1q[q] = om1; i1q[q] = oi1;
                } else m2q[q] = fminf(m2q[q], om1);
            }
        }
        if (l15 == 0) {
#pragma unroll
            for (int q = 0; q < 4; ++q) {
                const int rl = wr * 64 + rt * 16 + g * 4 + q;   // row within block
                tm1[rl * 2 + wc] = m1q[q];
                tm2[rl * 2 + wc] = m2q[q];
                ti1[rl * 2 + wc] = i1q[q];
            }
        }
    }
    __syncthreads();
    if (tid < BM) {
        float m1 = tm1[tid * 2], m2 = tm2[tid * 2]; int i1 = ti1[tid * 2];
        const float bm1 = tm1[tid * 2 + 1], bm2 = tm2[tid * 2 + 1]; const int bi = ti1[tid * 2 + 1];
        if (bm1 < m1 || (bm1 == m1 && bi < i1)) { m2 = fminf(m1, bm2); m1 = bm1; i1 = bi; }
        else m2 = fminf(m2, bm1);
        const size_t row = (size_t)rb * BM + tid;
        pm1[row * NCB + cb] = m1;
        pm2[row * NCB + cb] = m2;
        pidx[row * NCB + cb] = i1;
    }
}

// ---------------------------------------------------------------- merge 8 partials per row
__global__ __launch_bounds__(256) void k_merge(
    const float* __restrict__ pm1, const float* __restrict__ pm2, const int* __restrict__ pidx,
    float* __restrict__ row_s, int* __restrict__ row_idx,
    int* __restrict__ suspects, int* __restrict__ n_suspect)
{
    const int row = blockIdx.x * 256 + threadIdx.x;
    float m1 = INFINITY, m2 = INFINITY; int i1 = 0x7fffffff;
#pragma unroll
    for (int cb = 0; cb < NCB; ++cb) {
        const float bm1 = pm1[(size_t)row * NCB + cb];
        const float bm2 = pm2[(size_t)row * NCB + cb];
        const int   bi  = pidx[(size_t)row * NCB + cb];
        if (bm1 < m1 || (bm1 == m1 && bi < i1)) { m2 = fminf(m1, bm2); m1 = bm1; i1 = bi; }
        else m2 = fminf(m2, bm1);
    }
    row_s[row] = m1;
    row_idx[row] = i1;
    if (m2 - m1 < GAP_TAU) {   // fp16 noise could have reordered: exact re-check
        const int p = atomicAdd(n_suspect, 1);
        suspects[p] = row;
    }
}

// ---------------------------------------------------------------- fp64 re-check of near-ties
// Block per suspect (grid-strided). Block-filter via pm1: only code-blocks within
// FILT_TAU of the global partial min are scanned (typically 1 of 8). Thread-per-code:
// no shuffles in the hot loop, two independent fp64 accumulators per code.
__global__ __launch_bounds__(256) void k_repair(
    const float* __restrict__ A, const float* __restrict__ W,
    const float* __restrict__ pm1,
    const int* __restrict__ suspects, const int* __restrict__ n_suspect,
    float* __restrict__ row_s, int* __restrict__ row_idx)
{
    __shared__ float xrow[DDIM];
    __shared__ double wbest[4]; __shared__ int wbi[4];
    __shared__ double xps[4];
    __shared__ int qcb[NCB];
    __shared__ int nq;
    const int ns = *n_suspect;
    const int tid = threadIdx.x;
    const int wid = tid >> 6, lane = tid & 63;

    for (int s = blockIdx.x; s < ns; s += gridDim.x) {
        const int row = suspects[s];
        __syncthreads();   // previous iteration done with shared
        for (int i = tid; i < DDIM; i += 256) xrow[i] = A[(size_t)row * DDIM + i];
        if (tid == 0) {
            float gmin = INFINITY;
#pragma unroll
            for (int cb = 0; cb < NCB; ++cb) gmin = fminf(gmin, pm1[(size_t)row * NCB + cb]);
            int n = 0;
#pragma unroll
            for (int cb = 0; cb < NCB; ++cb)
                if (pm1[(size_t)row * NCB + cb] <= gmin + FILT_TAU) qcb[n++] = cb;
            nq = n;
        }
        __syncthreads();

        // xsq in fp64 (each wave reduces its tid-stripe; combined at the end)
        double xp = 0.0;
        for (int i = tid; i < DDIM; i += 256) { const double t = (double)xrow[i]; xp = fma(t, t, xp); }
        xp = waveRedAdd(xp);
        if (lane == 0) xps[wid] = xp;

        double best = 1e300; int bi = 0x7fffffff;
        const int ncand = nq * BK;
        for (int ci = tid; ci < ncand; ci += 256) {
            const int k = qcb[ci >> 7] * BK + (ci & (BK - 1));
            const float* wr = W + (size_t)k * DDIM;
            double d0 = 0.0, d1 = 0.0;
            for (int i = 0; i < DDIM; i += 4) {
                const float4 wv = *(const float4*)(wr + i);
                double t;
                t = (double)xrow[i + 0] - (double)wv.x; d0 = fma(t, t, d0);
                t = (double)xrow[i + 1] - (double)wv.y; d1 = fma(t, t, d1);
                t = (double)xrow[i + 2] - (double)wv.z; d0 = fma(t, t, d0);
                t = (double)xrow[i + 3] - (double)wv.w; d1 = fma(t, t, d1);
            }
            const double d = d0 + d1;
            if (d < best || (d == best && k < bi)) { best = d; bi = k; }
        }
        // wave reduce (min, tiebreak smaller index)
#pragma unroll
        for (int o = 32; o; o >>= 1) {
            const double ob = __shfl_xor(best, o);
            const int oi = __shfl_xor(bi, o);
            if (ob < best || (ob == best && oi < bi)) { best = ob; bi = oi; }
        }
        if (lane == 0) { wbest[wid] = best; wbi[wid] = bi; }
        __syncthreads();
        if (tid == 0) {
            double b = wbest[0]; int i1 = wbi[0];
#pragma unroll
            for (int w = 1; w < 4; ++w)
                if (wbest[w] < b || (wbest[w] == b && wbi[w] < i1)) { b = wbest[w]; i1 = wbi[w]; }
            row_idx[row] = i1;
            row_s[row] = (float)(b - (xps[0] + xps[1] + xps[2] + xps[3]));   // score form (dist - xsq)
        }
    }
}

// ---------------------------------------------------------------- quantize + losses + idx/min_d outputs
__global__ __launch_bounds__(256) void k_quantize(
    const float* __restrict__ A, const float* __restrict__ W,
    const float* __restrict__ row_s, const int* __restrict__ row_idx,
    float* __restrict__ out, float* __restrict__ counts,
    unsigned int* __restrict__ n_valid, double* __restrict__ sum_sqerr)
{
    const int wid = threadIdx.x >> 6, lane = threadIdx.x & 63;
    __shared__ double s_sum[4];
    __shared__ unsigned s_val[4];
    double wsum = 0.0; unsigned wval = 0;

#pragma unroll 1
    for (int it = 0; it < NROWS / (QGRID * 4); ++it) {
        const int row = (it * QGRID + blockIdx.x) * 4 + wid;
        const float* x = A + (size_t)row * DDIM;
        float4 xv[3];
#pragma unroll
        for (int j = 0; j < 3; ++j) xv[j] = *(const float4*)(x + (lane + 64 * j) * 4);
        float xsq = 0.f;
#pragma unroll
        for (int j = 0; j < 3; ++j)
            xsq += xv[j].x * xv[j].x + xv[j].y * xv[j].y + xv[j].z * xv[j].z + xv[j].w * xv[j].w;
        xsq = waveRedAdd(xsq);
        const bool valid = xsq > 1e-12f;            // norm > 1e-6
        const float maskf = valid ? 1.f : 0.f;
        const int idx = row_idx[row];
        const int idxm = valid ? idx : 0;
        const float* w = W + (size_t)idx * DDIM;
        float* oq = out + (size_t)row * DDIM;
        float e2 = 0.f;
#pragma unroll
        for (int j = 0; j < 3; ++j) {
            const float4 wvv = *(const float4*)(w + (lane + 64 * j) * 4);
            const float xs[4] = {xv[j].x, xv[j].y, xv[j].z, xv[j].w};
            const float ws[4] = {wvv.x, wvv.y, wvv.z, wvv.w};
            float os[4];
#pragma unroll
            for (int c = 0; c < 4; ++c) {
                const float q = ws[c] * maskf;          // q_flat = weight[idx] * mask
                os[c] = xs[c] + (q - xs[c]);            // quantized_st
                const float d = xs[c] - q;
                e2 += d * d;
            }
            float4 ov; ov.x = os[0]; ov.y = os[1]; ov.z = os[2]; ov.w = os[3];
            *(float4*)(oq + (lane + 64 * j) * 4) = ov;
        }
        e2 = waveRedAdd(e2);
        if (lane == 0) {
            wsum += (double)(maskf * e2);
            if (valid) {
                ++wval;
                atomicAdd(&counts[idxm], 1.0f);   // 1024 bins -> low contention
            }
            out[OUT_IDX + row]  = (float)idxm;
            out[OUT_MIND + row] = valid ? (xsq + row_s[row]) : 0.f;
        }
    }

    if (lane == 0) { s_sum[wid] = wsum; s_val[wid] = wval; }
    __syncthreads();
    if (threadIdx.x == 0) {
        atomicAdd(sum_sqerr, s_sum[0] + s_sum[1] + s_sum[2] + s_sum[3]);
        atomicAdd(n_valid, s_val[0] + s_val[1] + s_val[2] + s_val[3]);
    }
}

// ---------------------------------------------------------------- scalar losses
__global__ __launch_bounds__(256) void k_final(
    const float* __restrict__ counts, const unsigned int* __restrict__ n_valid,
    const double* __restrict__ sum_sqerr, float* __restrict__ out)
{
    const int t = threadIdx.x;
    const float nv = (float)(*n_valid);
    double ent = 0.0;
    for (int k = t; k < KCODES; k += 256) {
        const float p = counts[k] / nv;
        ent += (double)(p * logf(p + 1e-10f));
    }
    ent = waveRedAdd(ent);
    __shared__ double ps[4];
    if ((t & 63) == 0) ps[t >> 6] = ent;
    __syncthreads();
    if (t == 0) {
        const double e = ps[0] + ps[1] + ps[2] + ps[3];
        const double perp = exp(-e);
        const double ploss = -log(perp + 1e-10);
        const double commit = *sum_sqerr / ((double)(*n_valid) * (double)DDIM);
        out[OUT_LOSS] = (float)(0.25 * commit + 0.1 * ploss);
        out[OUT_PERP] = (float)perp;
    }
}

// ----------------------------------------------------------------
extern "C" void kernel_launch(void* const* d_in, const int* in_sizes, int n_in,
                              void* d_out, int out_size, void* d_ws, size_t ws_size,
                              hipStream_t stream) {
    const float* A = (const float*)d_in[0];   // [65536, 768]
    const float* W = (const float*)d_in[1];   // [1024, 768]
    float* out = (float*)d_out;
    char* ws = (char*)d_ws;
    if (ws_size < (size_t)WS_END) return;     // needs ~6.8 MB scratch

    double*   sum_sqerr = (double*)(ws + WS_SUM);
    int*      n_suspect = (int*)(ws + WS_NSUS);
    unsigned* n_valid   = (unsigned*)(ws + WS_NVAL);
    float*    counts    = (float*)(ws + WS_COUNTS);
    float*    wsq       = (float*)(ws + WS_WSQ);
    float*    row_s     = (float*)(ws + WS_ROWS);
    int*      row_idx   = (int*)(ws + WS_ROWI);
    int*      suspects  = (int*)(ws + WS_SUSP);
    float*    pm1       = (float*)(ws + WS_PM1);
    float*    pm2       = (float*)(ws + WS_PM2);
    int*      pidx      = (int*)(ws + WS_PIDX);

    hipLaunchKernelGGL(k_init, dim3(1), dim3(256), 0, stream, counts, n_suspect, n_valid, sum_sqerr);
    hipLaunchKernelGGL(k_wsq, dim3(KCODES), dim3(256), 0, stream, W, wsq);
    hipLaunchKernelGGL(k_partials, dim3((NROWS / BM) * NCB), dim3(256), 0, stream, A, W, wsq, pm1, pm2, pidx);
    hipLaunchKernelGGL(k_merge, dim3(NROWS / 256), dim3(256), 0, stream, pm1, pm2, pidx, row_s, row_idx, suspects, n_suspect);
    hipLaunchKernelGGL(k_repair, dim3(RGRID), dim3(256), 0, stream, A, W, pm1, suspects, n_suspect, row_s, row_idx);
    hipLaunchKernelGGL(k_quantize, dim3(QGRID), dim3(256), 0, stream, A, W, row_s, row_idx, out, counts, n_valid, sum_sqerr);
    hipLaunchKernelGGL(k_final, dim3(1), dim3(256), 0, stream, counts, n_valid, sum_sqerr, out);
}

// Round 6
// 482.357 us; speedup vs baseline: 13.8341x; 1.0351x over previous
//
#include <hip/hip_runtime.h>
#include <hip/hip_bf16.h>
#include <math.h>

// Problem constants
#define NROWS 65536      // 32*2048
#define DDIM  768
#define KCODES 1024
#define NCB   8          // code blocks (KCODES / BK)
#define BM    128        // rows per block tile
#define BK    128        // codes per block tile
#define KC    32         // K-chunk for fallback kernel
#define NCH   (DDIM / KC)
#define BK2   64         // K-chunk (fp16) for gload_lds kernel
#define NCH2  (DDIM / BK2)
#define GAP_TAU  0.4f    // fp16 score-error guard band (~18 sigma); near-ties re-checked in fp64
#define FILT_TAU 0.8f    // repair block-filter margin (2x guard band)
#define RGRID 512        // k_repair blocks
#define QGRID 2048       // k_quantize blocks

// ---- output offsets (d_out is float32, outputs concatenated in return order)
#define OUT_LOSS ((size_t)NROWS * DDIM)
#define OUT_IDX  (OUT_LOSS + 1)
#define OUT_MIND (OUT_IDX + NROWS)
#define OUT_PERP (OUT_MIND + NROWS)

// ---- workspace offsets (bytes)
#define WS_SUM    0                              // double sum_sqerr
#define WS_NSUS   8                              // int n_suspect
#define WS_NVAL   12                             // unsigned n_valid
#define WS_COUNTS 256                            // float[KCODES]
#define WS_WSQ    (WS_COUNTS + 4*KCODES)         // float[KCODES]
#define WS_ROWS   (WS_WSQ + 4*KCODES)            // float[NROWS] row min score (dist - xsq)
#define WS_ROWI   (WS_ROWS + 4*NROWS)            // int[NROWS] row argmin
#define WS_SUSP   (WS_ROWI + 4*NROWS)            // int[NROWS] suspect rows
#define WS_PM1    (WS_SUSP + 4*NROWS)            // float[NROWS*NCB] partial min
#define WS_PM2    (WS_PM1 + (size_t)4*NROWS*NCB) // float[NROWS*NCB] partial 2nd min
#define WS_PIDX   (WS_PM2 + (size_t)4*NROWS*NCB) // int[NROWS*NCB] partial argmin
#define WS_END    (WS_PIDX + (size_t)4*NROWS*NCB)
// fp16 mirrors (pre-swizzled), used only if ws_size permits (~105 MB total)
#define WS_AF16   ((WS_END + 255) & ~(size_t)255)
#define WS_WF16   (WS_AF16 + (size_t)NROWS * DDIM * 2)
#define WS_END2   (WS_WF16 + (size_t)KCODES * DDIM * 2)

typedef __attribute__((ext_vector_type(8))) _Float16 half8;  // 8 f16 = 4 VGPRs (MFMA A/B frag)
typedef __attribute__((ext_vector_type(4))) float f32x4;     // MFMA C/D frag

// async global->LDS, 16B per lane; LDS dest = wave-uniform base + lane*16
#define GLOAD16(gsrc, ldst) \
    __builtin_amdgcn_global_load_lds( \
        (const __attribute__((address_space(1))) unsigned int*)(gsrc), \
        (__attribute__((address_space(3))) unsigned int*)(ldst), 16, 0, 0)

template <typename T>
__device__ inline T waveRedAdd(T v) {
#pragma unroll
    for (int o = 32; o; o >>= 1) v += __shfl_xor(v, o);
    return v;
}

__device__ inline ushort f2h(float f) {
    union { _Float16 h; ushort u; } c;
    c.h = (_Float16)f;   // RTN-even
    return c.u;
}

// ---------------------------------------------------------------- init
__global__ void k_init(float* counts, int* n_suspect, unsigned* n_valid, double* sum_sqerr) {
    const int t = threadIdx.x;
    if (t == 0) { *n_suspect = 0; *n_valid = 0u; *sum_sqerr = 0.0; }
    for (int k = t; k < KCODES; k += 256) counts[k] = 0.f;
}

// ---------------------------------------------------------------- fp32 -> fp16 pre-convert (slot-swizzled)
// Row layout: 12 chunks of 64 fp16; each chunk = 8 slots of 16B; slot s stored at s^(row&7).
// This bakes the LDS read-swizzle into global memory so the GEMM can use linear
// global_load_lds staging and still get conflict-free ds_read_b128 (rule #21 / m173).
#define ASLOTS (NROWS * (DDIM / 8))
#define TSLOTS ((NROWS + KCODES) * (DDIM / 8))
__global__ __launch_bounds__(256) void k_convert(
    const float* __restrict__ A, const float* __restrict__ W,
    ushort* __restrict__ Af16, ushort* __restrict__ Wf16)
{
    for (int gidx = blockIdx.x * 256 + threadIdx.x; gidx < TSLOTS; gidx += gridDim.x * 256) {
        const float* src; ushort* dst; int sid;
        if (gidx < ASLOTS) { src = A; dst = Af16; sid = gidx; }
        else { src = W; dst = Wf16; sid = gidx - ASLOTS; }
        const int row = sid / 96;           // 96 slots per row
        const int sl = sid - row * 96;
        const int ch = sl >> 3, s = sl & 7;
        const float* p = src + (size_t)row * DDIM + ch * 64 + s * 8;
        const float4 a = *(const float4*)p;
        const float4 b = *(const float4*)(p + 4);
        uint4 v;
        v.x = ((unsigned)f2h(a.y) << 16) | f2h(a.x);
        v.y = ((unsigned)f2h(a.w) << 16) | f2h(a.z);
        v.z = ((unsigned)f2h(b.y) << 16) | f2h(b.x);
        v.w = ((unsigned)f2h(b.w) << 16) | f2h(b.z);
        *(uint4*)(dst + (size_t)row * DDIM + ch * 64 + ((s ^ (row & 7)) << 3)) = v;
    }
}

// ---------------------------------------------------------------- ||e_k||^2 (exact fp32)
__global__ __launch_bounds__(256) void k_wsq(const float* __restrict__ W, float* __restrict__ wsq) {
    const int k = blockIdx.x;
    const int t = threadIdx.x;
    const float* w = W + (size_t)k * DDIM;
    const float a = w[t], b = w[t + 256], c = w[t + 512];
    float s = a * a + b * b + c * c;
    s = waveRedAdd(s);
    __shared__ float p[4];
    if ((t & 63) == 0) p[t >> 6] = s;
    __syncthreads();
    if (t == 0) wsq[k] = (p[0] + p[1]) + (p[2] + p[3]);
}

// ---------------------------------------------------------------- main GEMM (fp16 MFMA, gload_lds staging)
// m97 structure: 128x128 tile, BK2=64, single-buffered LDS, 2 barriers/chunk,
// global_load_lds width-16 (no VALU staging, no cvt — data pre-converted/pre-swizzled).
__global__ __launch_bounds__(256, 2) void k_partials_g(
    const ushort* __restrict__ Af16, const ushort* __restrict__ Wf16,
    const float* __restrict__ wsq,
    float* __restrict__ pm1, float* __restrict__ pm2, int* __restrict__ pidx)
{
    __shared__ __align__(16) ushort lds[2 * BM * BK2];   // As[128][64] | Ws[128][64] (swizzled fp16)
    ushort* As = lds;
    ushort* Ws = lds + BM * BK2;

    // XCD-panel swizzle: each XCD owns a contiguous band of 64 row-panels, cb fastest.
    const int bid = blockIdx.x;
    const int rb = ((bid & 7) << 6) | (bid >> 6);
    const int cb = (bid >> 3) & 7;

    const int tid = threadIdx.x;
    const int wid = tid >> 6, lane = tid & 63;
    const int wr = wid >> 1, wc = wid & 1;       // wave quadrant (row-half, col-half)
    const int l15 = lane & 15, g = lane >> 4;    // frag row/col + k-group

    const ushort* Ab = Af16 + (size_t)rb * BM * DDIM;
    const ushort* Wb = Wf16 + (size_t)cb * BK * DDIM;

    const int srow = lane >> 3;     // row within an 8-row segment
    const int sslot = lane & 7;     // 16B slot within a 128B row-chunk

    f32x4 acc[4][4];
#pragma unroll
    for (int rt = 0; rt < 4; ++rt)
#pragma unroll
        for (int ct = 0; ct < 4; ++ct) acc[rt][ct] = (f32x4)0.f;

#pragma unroll 1
    for (int ch = 0; ch < NCH2; ++ch) {
        __syncthreads();   // previous compute done reading LDS
        // stage 16 KB A + 16 KB W: 16 segments of 1 KB each, 4 waves x 4 issues
#pragma unroll
        for (int i = 0; i < 4; ++i) {
            const int seg = (i << 2) | wid;                 // wave-uniform
            const int row = (seg << 3) | srow;              // 0..127
            GLOAD16(Ab + (size_t)row * DDIM + ch * BK2 + sslot * 8, (char*)As + (seg << 10));
            GLOAD16(Wb + (size_t)row * DDIM + ch * BK2 + sslot * 8, (char*)Ws + (seg << 10));
        }
        __syncthreads();   // vmcnt drained by barrier semantics -> LDS ready
#pragma unroll
        for (int h = 0; h < 2; ++h) {   // two 16x16x32 k-halves of the 64-chunk
            half8 af[4], bf[4];
#pragma unroll
            for (int rt = 0; rt < 4; ++rt) {
                const int r = wr * 64 + rt * 16 + l15;
                af[rt] = *(const half8*)(As + r * BK2 + ((((h << 2) | g) ^ (r & 7)) << 3));
                const int c = wc * 64 + rt * 16 + l15;
                bf[rt] = *(const half8*)(Ws + c * BK2 + ((((h << 2) | g) ^ (c & 7)) << 3));
            }
#pragma unroll
            for (int rt = 0; rt < 4; ++rt)
#pragma unroll
                for (int ct = 0; ct < 4; ++ct)
                    acc[rt][ct] = __builtin_amdgcn_mfma_f32_16x16x32_f16(af[rt], bf[ct], acc[rt][ct], 0, 0, 0);
        }
    }

    // ---------------- epilogue: per-row (min, 2nd-min, argmin) over this 128-code tile
    // C/D layout: col = lane&15, row = (lane>>4)*4 + q  [m89]
    float wq[4];
#pragma unroll
    for (int ct = 0; ct < 4; ++ct) wq[ct] = wsq[cb * BK + wc * 64 + ct * 16 + l15];
    const int cbase = cb * BK + wc * 64 + l15;

    __syncthreads();   // staging reads drained; reuse LDS for the column-half merge
    float* tm1 = (float*)lds;          // [128][2]  (row-local, wc)
    float* tm2 = tm1 + 256;
    int*   ti1 = (int*)(tm2 + 256);

#pragma unroll
    for (int rt = 0; rt < 4; ++rt) {
        float m1q[4], m2q[4]; int i1q[4];
#pragma unroll
        for (int q = 0; q < 4; ++q) { m1q[q] = INFINITY; m2q[q] = INFINITY; i1q[q] = 0x7fffffff; }
#pragma unroll
        for (int ct = 0; ct < 4; ++ct) {
            const int col = cbase + ct * 16;
#pragma unroll
            for (int q = 0; q < 4; ++q) {
                const float s = fmaf(-2.f, acc[rt][ct][q], wq[ct]);
                if (s < m1q[q]) { m2q[q] = m1q[q]; m1q[q] = s; i1q[q] = col; }
                else if (s < m2q[q]) m2q[q] = s;
            }
        }
#pragma unroll
        for (int msk = 1; msk <= 8; msk <<= 1) {
#pragma unroll
            for (int q = 0; q < 4; ++q) {
                const float om1 = __shfl_xor(m1q[q], msk);
                const float om2 = __shfl_xor(m2q[q], msk);
                const int   oi1 = __shfl_xor(i1q[q], msk);
                if (om1 < m1q[q] || (om1 == m1q[q] && oi1 < i1q[q])) {
                    m2q[q] = fminf(m1q[q], om2); m1q[q] = om1; i1q[q] = oi1;
                } else m2q[q] = fminf(m2q[q], om1);
            }
        }
        if (l15 == 0) {
#pragma unroll
            for (int q = 0; q < 4; ++q) {
                const int rl = wr * 64 + rt * 16 + g * 4 + q;   // row within block
                tm1[rl * 2 + wc] = m1q[q];
                tm2[rl * 2 + wc] = m2q[q];
                ti1[rl * 2 + wc] = i1q[q];
            }
        }
    }
    __syncthreads();
    if (tid < BM) {
        float m1 = tm1[tid * 2], m2 = tm2[tid * 2]; int i1 = ti1[tid * 2];
        const float bm1 = tm1[tid * 2 + 1], bm2 = tm2[tid * 2 + 1]; const int bi = ti1[tid * 2 + 1];
        if (bm1 < m1 || (bm1 == m1 && bi < i1)) { m2 = fminf(m1, bm2); m1 = bm1; i1 = bi; }
        else m2 = fminf(m2, bm1);
        const size_t row = (size_t)rb * BM + tid;
        pm1[row * NCB + cb] = m1;
        pm2[row * NCB + cb] = m2;
        pidx[row * NCB + cb] = i1;
    }
}

// ---------------------------------------------------------------- fallback GEMM (r5, fused cvt) if ws too small
__global__ __launch_bounds__(256, 2) void k_partials(
    const float* __restrict__ A, const float* __restrict__ W,
    const float* __restrict__ wsq,
    float* __restrict__ pm1, float* __restrict__ pm2, int* __restrict__ pidx)
{
    __shared__ __align__(16) ushort lds[2 * BM * KC];
    ushort* As = lds;
    ushort* Ws = lds + BM * KC;

    const int bid = blockIdx.x;
    const int rb = ((bid & 7) << 6) | (bid >> 6);
    const int cb = (bid >> 3) & 7;

    const int tid = threadIdx.x;
    const int wid = tid >> 6, lane = tid & 63;
    const int wr = wid >> 1, wc = wid & 1;
    const int l15 = lane & 15, g = lane >> 4;

    const float* Ab = A + (size_t)rb * BM * DDIM;
    const float* Wb = W + (size_t)cb * BK * DDIM;

    const int srow = tid >> 3;
    const int sk4  = (tid & 7) << 2;
    const int sg   = (tid & 7) >> 1;
    const int sh   = (tid & 1) << 2;

    int aOff[4], bOff[4];
#pragma unroll
    for (int rt = 0; rt < 4; ++rt) {
        const int r = wr * 64 + rt * 16 + l15;
        aOff[rt] = r * KC + ((g ^ ((r >> 1) & 3)) << 3);
        const int c = wc * 64 + rt * 16 + l15;
        bOff[rt] = c * KC + ((g ^ ((c >> 1) & 3)) << 3);
    }

    f32x4 acc[4][4];
#pragma unroll
    for (int rt = 0; rt < 4; ++rt)
#pragma unroll
        for (int ct = 0; ct < 4; ++ct) acc[rt][ct] = (f32x4)0.f;

    float4 av[4], wv[4];
#pragma unroll
    for (int i = 0; i < 4; ++i) {
        av[i] = *(const float4*)(Ab + (size_t)(srow + 32 * i) * DDIM + sk4);
        wv[i] = *(const float4*)(Wb + (size_t)(srow + 32 * i) * DDIM + sk4);
    }

#pragma unroll 1
    for (int ch = 0; ch < NCH; ++ch) {
        __syncthreads();
#pragma unroll
        for (int i = 0; i < 4; ++i) {
            const int r = srow + 32 * i;
            const int wsl = r * KC + ((sg ^ ((r >> 1) & 3)) << 3) + sh;
            ushort4 ua; ua.x = f2h(av[i].x); ua.y = f2h(av[i].y); ua.z = f2h(av[i].z); ua.w = f2h(av[i].w);
            *(ushort4*)(As + wsl) = ua;
            ushort4 uw; uw.x = f2h(wv[i].x); uw.y = f2h(wv[i].y); uw.z = f2h(wv[i].z); uw.w = f2h(wv[i].w);
            *(ushort4*)(Ws + wsl) = uw;
        }
        __syncthreads();
        if (ch + 1 < NCH) {
            const int d0 = (ch + 1) * KC + sk4;
#pragma unroll
            for (int i = 0; i < 4; ++i) {
                av[i] = *(const float4*)(Ab + (size_t)(srow + 32 * i) * DDIM + d0);
                wv[i] = *(const float4*)(Wb + (size_t)(srow + 32 * i) * DDIM + d0);
            }
        }
        half8 af[4], bf[4];
#pragma unroll
        for (int rt = 0; rt < 4; ++rt) af[rt] = *(const half8*)(As + aOff[rt]);
#pragma unroll
        for (int ct = 0; ct < 4; ++ct) bf[ct] = *(const half8*)(Ws + bOff[ct]);
#pragma unroll
        for (int rt = 0; rt < 4; ++rt)
#pragma unroll
            for (int ct = 0; ct < 4; ++ct)
                acc[rt][ct] = __builtin_amdgcn_mfma_f32_16x16x32_f16(af[rt], bf[ct], acc[rt][ct], 0, 0, 0);
    }

    float wq[4];
#pragma unroll
    for (int ct = 0; ct < 4; ++ct) wq[ct] = wsq[cb * BK + wc * 64 + ct * 16 + l15];
    const int cbase = cb * BK + wc * 64 + l15;

    __syncthreads();
    float* tm1 = (float*)lds;
    float* tm2 = tm1 + 256;
    int*   ti1 = (int*)(tm2 + 256);

#pragma unroll
    for (int rt = 0; rt < 4; ++rt) {
        float m1q[4], m2q[4]; int i1q[4];
#pragma unroll
        for (int q = 0; q < 4; ++q) { m1q[q] = INFINITY; m2q[q] = INFINITY; i1q[q] = 0x7fffffff; }
#pragma unroll
        for (int ct = 0; ct < 4; ++ct) {
            const int col = cbase + ct * 16;
#pragma unroll
            for (int q = 0; q < 4; ++q) {
                const float s = fmaf(-2.f, acc[rt][ct][q], wq[ct]);
                if (s < m1q[q]) { m2q[q] = m1q[q]; m1q[q] = s; i1q[q] = col; }
                else if (s < m2q[q]) m2q[q] = s;
            }
        }
#pragma unroll
        for (int msk = 1; msk <= 8; msk <<= 1) {
#pragma unroll
            for (int q = 0; q < 4; ++q) {
                const float om1 = __shfl_xor(m1q[q], msk);
                const float om2 = __shfl_xor(m2q[q], msk);
                const int   oi1 = __shfl_xor(i1q[q], msk);
                if (om1 < m1q[q] || (om1 == m1q[q] && oi1 < i1q[q])) {
                    m2q[q] = fminf(m1q[q], om2); m1q[q] = om1; i1q[q] = oi1;
                } else m2q[q] = fminf(m2q[q], om1);
            }
        }
        if (l15 == 0) {
#pragma unroll
            for (int q = 0; q < 4; ++q) {
                const int rl = wr * 64 + rt * 16 + g * 4 + q;
                tm1[rl * 2 + wc] = m1q[q];
                tm2[rl * 2 + wc] = m2q[q];
                ti1[rl * 2 + wc] = i1q[q];
            }
        }
    }
    __syncthreads();
    if (tid < BM) {
        float m1 = tm1[tid * 2], m2 = tm2[tid * 2]; int i1 = ti1[tid * 2];
        const float bm1 = tm1[tid * 2 + 1], bm2 = tm2[tid * 2 + 1]; const int bi = ti1[tid * 2 + 1];
        if (bm1 < m1 || (bm1 == m1 && bi < i1)) { m2 = fminf(m1, bm2); m1 = bm1; i1 = bi; }
        else m2 = fminf(m2, bm1);
        const size_t row = (size_t)rb * BM + tid;
        pm1[row * NCB + cb] = m1;
        pm2[row * NCB + cb] = m2;
        pidx[row * NCB + cb] = i1;
    }
}

// ---------------------------------------------------------------- merge 8 partials per row
__global__ __launch_bounds__(256) void k_merge(
    const float* __restrict__ pm1, const float* __restrict__ pm2, const int* __restrict__ pidx,
    float* __restrict__ row_s, int* __restrict__ row_idx,
    int* __restrict__ suspects, int* __restrict__ n_suspect)
{
    const int row = blockIdx.x * 256 + threadIdx.x;
    float m1 = INFINITY, m2 = INFINITY; int i1 = 0x7fffffff;
#pragma unroll
    for (int cb = 0; cb < NCB; ++cb) {
        const float bm1 = pm1[(size_t)row * NCB + cb];
        const float bm2 = pm2[(size_t)row * NCB + cb];
        const int   bi  = pidx[(size_t)row * NCB + cb];
        if (bm1 < m1 || (bm1 == m1 && bi < i1)) { m2 = fminf(m1, bm2); m1 = bm1; i1 = bi; }
        else m2 = fminf(m2, bm1);
    }
    row_s[row] = m1;
    row_idx[row] = i1;
    if (m2 - m1 < GAP_TAU) {   // fp16 noise could have reordered: exact re-check
        const int p = atomicAdd(n_suspect, 1);
        suspects[p] = row;
    }
}

// ---------------------------------------------------------------- fp64 re-check of near-ties
__global__ __launch_bounds__(256) void k_repair(
    const float* __restrict__ A, const float* __restrict__ W,
    const float* __restrict__ pm1,
    const int* __restrict__ suspects, const int* __restrict__ n_suspect,
    float* __restrict__ row_s, int* __restrict__ row_idx)
{
    __shared__ float xrow[DDIM];
    __shared__ double wbest[4]; __shared__ int wbi[4];
    __shared__ double xps[4];
    __shared__ int qcb[NCB];
    __shared__ int nq;
    const int ns = *n_suspect;
    const int tid = threadIdx.x;
    const int wid = tid >> 6, lane = tid & 63;

    for (int s = blockIdx.x; s < ns; s += gridDim.x) {
        const int row = suspects[s];
        __syncthreads();
        for (int i = tid; i < DDIM; i += 256) xrow[i] = A[(size_t)row * DDIM + i];
        if (tid == 0) {
            float gmin = INFINITY;
#pragma unroll
            for (int cb = 0; cb < NCB; ++cb) gmin = fminf(gmin, pm1[(size_t)row * NCB + cb]);
            int n = 0;
#pragma unroll
            for (int cb = 0; cb < NCB; ++cb)
                if (pm1[(size_t)row * NCB + cb] <= gmin + FILT_TAU) qcb[n++] = cb;
            nq = n;
        }
        __syncthreads();

        double xp = 0.0;
        for (int i = tid; i < DDIM; i += 256) { const double t = (double)xrow[i]; xp = fma(t, t, xp); }
        xp = waveRedAdd(xp);
        if (lane == 0) xps[wid] = xp;

        double best = 1e300; int bi = 0x7fffffff;
        const int ncand = nq * BK;
        for (int ci = tid; ci < ncand; ci += 256) {
            const int k = qcb[ci >> 7] * BK + (ci & (BK - 1));
            const float* wr = W + (size_t)k * DDIM;
            double d0 = 0.0, d1 = 0.0;
            for (int i = 0; i < DDIM; i += 4) {
                const float4 wv = *(const float4*)(wr + i);
                double t;
                t = (double)xrow[i + 0] - (double)wv.x; d0 = fma(t, t, d0);
                t = (double)xrow[i + 1] - (double)wv.y; d1 = fma(t, t, d1);
                t = (double)xrow[i + 2] - (double)wv.z; d0 = fma(t, t, d0);
                t = (double)xrow[i + 3] - (double)wv.w; d1 = fma(t, t, d1);
            }
            const double d = d0 + d1;
            if (d < best || (d == best && k < bi)) { best = d; bi = k; }
        }
#pragma unroll
        for (int o = 32; o; o >>= 1) {
            const double ob = __shfl_xor(best, o);
            const int oi = __shfl_xor(bi, o);
            if (ob < best || (ob == best && oi < bi)) { best = ob; bi = oi; }
        }
        if (lane == 0) { wbest[wid] = best; wbi[wid] = bi; }
        __syncthreads();
        if (tid == 0) {
            double b = wbest[0]; int i1 = wbi[0];
#pragma unroll
            for (int w = 1; w < 4; ++w)
                if (wbest[w] < b || (wbest[w] == b && wbi[w] < i1)) { b = wbest[w]; i1 = wbi[w]; }
            row_idx[row] = i1;
            row_s[row] = (float)(b - (xps[0] + xps[1] + xps[2] + xps[3]));
        }
    }
}

// ---------------------------------------------------------------- quantize + losses + idx/min_d outputs
__global__ __launch_bounds__(256) void k_quantize(
    const float* __restrict__ A, const float* __restrict__ W,
    const float* __restrict__ row_s, const int* __restrict__ row_idx,
    float* __restrict__ out, float* __restrict__ counts,
    unsigned int* __restrict__ n_valid, double* __restrict__ sum_sqerr)
{
    const int wid = threadIdx.x >> 6, lane = threadIdx.x & 63;
    __shared__ double s_sum[4];
    __shared__ unsigned s_val[4];
    double wsum = 0.0; unsigned wval = 0;

#pragma unroll 1
    for (int it = 0; it < NROWS / (QGRID * 4); ++it) {
        const int row = (it * QGRID + blockIdx.x) * 4 + wid;
        const float* x = A + (size_t)row * DDIM;
        float4 xv[3];
#pragma unroll
        for (int j = 0; j < 3; ++j) xv[j] = *(const float4*)(x + (lane + 64 * j) * 4);
        float xsq = 0.f;
#pragma unroll
        for (int j = 0; j < 3; ++j)
            xsq += xv[j].x * xv[j].x + xv[j].y * xv[j].y + xv[j].z * xv[j].z + xv[j].w * xv[j].w;
        xsq = waveRedAdd(xsq);
        const bool valid = xsq > 1e-12f;            // norm > 1e-6
        const float maskf = valid ? 1.f : 0.f;
        const int idx = row_idx[row];
        const int idxm = valid ? idx : 0;
        const float* w = W + (size_t)idx * DDIM;
        float* oq = out + (size_t)row * DDIM;
        float e2 = 0.f;
#pragma unroll
        for (int j = 0; j < 3; ++j) {
            const float4 wvv = *(const float4*)(w + (lane + 64 * j) * 4);
            const float xs[4] = {xv[j].x, xv[j].y, xv[j].z, xv[j].w};
            const float ws[4] = {wvv.x, wvv.y, wvv.z, wvv.w};
            float os[4];
#pragma unroll
            for (int c = 0; c < 4; ++c) {
                const float q = ws[c] * maskf;          // q_flat = weight[idx] * mask
                os[c] = xs[c] + (q - xs[c]);            // quantized_st
                const float d = xs[c] - q;
                e2 += d * d;
            }
            float4 ov; ov.x = os[0]; ov.y = os[1]; ov.z = os[2]; ov.w = os[3];
            *(float4*)(oq + (lane + 64 * j) * 4) = ov;
        }
        e2 = waveRedAdd(e2);
        if (lane == 0) {
            wsum += (double)(maskf * e2);
            if (valid) {
                ++wval;
                atomicAdd(&counts[idxm], 1.0f);
            }
            out[OUT_IDX + row]  = (float)idxm;
            out[OUT_MIND + row] = valid ? (xsq + row_s[row]) : 0.f;
        }
    }

    if (lane == 0) { s_sum[wid] = wsum; s_val[wid] = wval; }
    __syncthreads();
    if (threadIdx.x == 0) {
        atomicAdd(sum_sqerr, s_sum[0] + s_sum[1] + s_sum[2] + s_sum[3]);
        atomicAdd(n_valid, s_val[0] + s_val[1] + s_val[2] + s_val[3]);
    }
}

// ---------------------------------------------------------------- scalar losses
__global__ __launch_bounds__(256) void k_final(
    const float* __restrict__ counts, const unsigned int* __restrict__ n_valid,
    const double* __restrict__ sum_sqerr, float* __restrict__ out)
{
    const int t = threadIdx.x;
    const float nv = (float)(*n_valid);
    double ent = 0.0;
    for (int k = t; k < KCODES; k += 256) {
        const float p = counts[k] / nv;
        ent += (double)(p * logf(p + 1e-10f));
    }
    ent = waveRedAdd(ent);
    __shared__ double ps[4];
    if ((t & 63) == 0) ps[t >> 6] = ent;
    __syncthreads();
    if (t == 0) {
        const double e = ps[0] + ps[1] + ps[2] + ps[3];
        const double perp = exp(-e);
        const double ploss = -log(perp + 1e-10);
        const double commit = *sum_sqerr / ((double)(*n_valid) * (double)DDIM);
        out[OUT_LOSS] = (float)(0.25 * commit + 0.1 * ploss);
        out[OUT_PERP] = (float)perp;
    }
}

// ----------------------------------------------------------------
extern "C" void kernel_launch(void* const* d_in, const int* in_sizes, int n_in,
                              void* d_out, int out_size, void* d_ws, size_t ws_size,
                              hipStream_t stream) {
    const float* A = (const float*)d_in[0];   // [65536, 768]
    const float* W = (const float*)d_in[1];   // [1024, 768]
    float* out = (float*)d_out;
    char* ws = (char*)d_ws;
    if (ws_size < (size_t)WS_END) return;     // needs >=6.8 MB scratch

    double*   sum_sqerr = (double*)(ws + WS_SUM);
    int*      n_suspect = (int*)(ws + WS_NSUS);
    unsigned* n_valid   = (unsigned*)(ws + WS_NVAL);
    float*    counts    = (float*)(ws + WS_COUNTS);
    float*    wsq       = (float*)(ws + WS_WSQ);
    float*    row_s     = (float*)(ws + WS_ROWS);
    int*      row_idx   = (int*)(ws + WS_ROWI);
    int*      suspects  = (int*)(ws + WS_SUSP);
    float*    pm1       = (float*)(ws + WS_PM1);
    float*    pm2       = (float*)(ws + WS_PM2);
    int*      pidx      = (int*)(ws + WS_PIDX);
    ushort*   Af16      = (ushort*)(ws + WS_AF16);
    ushort*   Wf16      = (ushort*)(ws + WS_WF16);

    const bool big = ws_size >= (size_t)WS_END2;   // ~105 MB: fp16-preconvert path

    hipLaunchKernelGGL(k_init, dim3(1), dim3(256), 0, stream, counts, n_suspect, n_valid, sum_sqerr);
    if (big)
        hipLaunchKernelGGL(k_convert, dim3(2048), dim3(256), 0, stream, A, W, Af16, Wf16);
    hipLaunchKernelGGL(k_wsq, dim3(KCODES), dim3(256), 0, stream, W, wsq);
    if (big)
        hipLaunchKernelGGL(k_partials_g, dim3((NROWS / BM) * NCB), dim3(256), 0, stream, Af16, Wf16, wsq, pm1, pm2, pidx);
    else
        hipLaunchKernelGGL(k_partials, dim3((NROWS / BM) * NCB), dim3(256), 0, stream, A, W, wsq, pm1, pm2, pidx);
    hipLaunchKernelGGL(k_merge, dim3(NROWS / 256), dim3(256), 0, stream, pm1, pm2, pidx, row_s, row_idx, suspects, n_suspect);
    hipLaunchKernelGGL(k_repair, dim3(RGRID), dim3(256), 0, stream, A, W, pm1, suspects, n_suspect, row_s, row_idx);
    hipLaunchKernelGGL(k_quantize, dim3(QGRID), dim3(256), 0, stream, A, W, row_s, row_idx, out, counts, n_valid, sum_sqerr);
    hipLaunchKernelGGL(k_final, dim3(1), dim3(256), 0, stream, counts, n_valid, sum_sqerr, out);
}

// Round 7
// 403.483 us; speedup vs baseline: 16.5384x; 1.1955x over previous
//
#include <hip/hip_runtime.h>
#include <hip/hip_bf16.h>
#include <math.h>

// Problem constants
#define NROWS 65536      // 32*2048
#define DDIM  768
#define KCODES 1024
#define NCB   8          // code blocks (KCODES / BK)
#define BM    128        // rows per block tile
#define BK    128        // codes per block tile
#define KC    32         // K-chunk for fallback kernel
#define NCH   (DDIM / KC)
#define BK2   64         // K-chunk (fp16) for gload_lds kernel
#define NCH2  (DDIM / BK2)
#define GAP_TAU  0.3f    // fp16 score-error guard band (~7.5 sigma); near-ties re-checked in fp64
#define FILT_TAU 0.6f    // repair block-filter margin (2x guard band)
#define RGRID 2048       // k_repair blocks
#define QGRID 2048       // k_quantize blocks

// ---- output offsets (d_out is float32, outputs concatenated in return order)
#define OUT_LOSS ((size_t)NROWS * DDIM)
#define OUT_IDX  (OUT_LOSS + 1)
#define OUT_MIND (OUT_IDX + NROWS)
#define OUT_PERP (OUT_MIND + NROWS)

// ---- workspace offsets (bytes)
#define WS_SUM    0                              // double sum_sqerr
#define WS_NSUS   8                              // int n_suspect
#define WS_NVAL   12                             // unsigned n_valid
#define WS_COUNTS 256                            // float[KCODES]
#define WS_WSQ    (WS_COUNTS + 4*KCODES)         // float[KCODES]
#define WS_ROWS   (WS_WSQ + 4*KCODES)            // float[NROWS] row min score (dist - xsq)
#define WS_ROWI   (WS_ROWS + 4*NROWS)            // int[NROWS] row argmin
#define WS_SUSP   (WS_ROWI + 4*NROWS)            // int[NROWS] suspect rows
#define WS_PM1    (WS_SUSP + 4*NROWS)            // float[NROWS*NCB] partial min
#define WS_PM2    (WS_PM1 + (size_t)4*NROWS*NCB) // float[NROWS*NCB] partial 2nd min
#define WS_PIDX   (WS_PM2 + (size_t)4*NROWS*NCB) // int[NROWS*NCB] partial argmin
#define WS_END    (WS_PIDX + (size_t)4*NROWS*NCB)
// fp16 mirrors (pre-swizzled), used only if ws_size permits (~105 MB total)
#define WS_AF16   ((WS_END + 255) & ~(size_t)255)
#define WS_WF16   (WS_AF16 + (size_t)NROWS * DDIM * 2)
#define WS_END2   (WS_WF16 + (size_t)KCODES * DDIM * 2)

typedef __attribute__((ext_vector_type(8))) _Float16 half8;  // 8 f16 = 4 VGPRs (MFMA A/B frag)
typedef __attribute__((ext_vector_type(4))) float f32x4;     // MFMA C/D frag

// async global->LDS, 16B per lane; LDS dest = wave-uniform base + lane*16
#define GLOAD16(gsrc, ldst) \
    __builtin_amdgcn_global_load_lds( \
        (const __attribute__((address_space(1))) unsigned int*)(gsrc), \
        (__attribute__((address_space(3))) unsigned int*)(ldst), 16, 0, 0)

template <typename T>
__device__ inline T waveRedAdd(T v) {
#pragma unroll
    for (int o = 32; o; o >>= 1) v += __shfl_xor(v, o);
    return v;
}

__device__ inline ushort f2h(float f) {
    union { _Float16 h; ushort u; } c;
    c.h = (_Float16)f;   // RTN-even
    return c.u;
}

// ---------------------------------------------------------------- init
__global__ void k_init(float* counts, int* n_suspect, unsigned* n_valid, double* sum_sqerr) {
    const int t = threadIdx.x;
    if (t == 0) { *n_suspect = 0; *n_valid = 0u; *sum_sqerr = 0.0; }
    for (int k = t; k < KCODES; k += 256) counts[k] = 0.f;
}

// ---------------------------------------------------------------- fp32 -> fp16 pre-convert (slot-swizzled)
// Row layout: 12 chunks of 64 fp16; each chunk = 8 slots of 16B; slot s stored at s^(row&7).
// Bakes the LDS read-swizzle into global memory so the GEMM uses linear global_load_lds
// staging and still gets conflict-free ds_read_b128 (rule #21 / m173).
#define ASLOTS (NROWS * (DDIM / 8))
#define TSLOTS ((NROWS + KCODES) * (DDIM / 8))
__global__ __launch_bounds__(256) void k_convert(
    const float* __restrict__ A, const float* __restrict__ W,
    ushort* __restrict__ Af16, ushort* __restrict__ Wf16)
{
    for (int gidx = blockIdx.x * 256 + threadIdx.x; gidx < TSLOTS; gidx += gridDim.x * 256) {
        const float* src; ushort* dst; int sid;
        if (gidx < ASLOTS) { src = A; dst = Af16; sid = gidx; }
        else { src = W; dst = Wf16; sid = gidx - ASLOTS; }
        const int row = sid / 96;           // 96 slots per row
        const int sl = sid - row * 96;
        const int ch = sl >> 3, s = sl & 7;
        const float* p = src + (size_t)row * DDIM + ch * 64 + s * 8;
        const float4 a = *(const float4*)p;
        const float4 b = *(const float4*)(p + 4);
        uint4 v;
        v.x = ((unsigned)f2h(a.y) << 16) | f2h(a.x);
        v.y = ((unsigned)f2h(a.w) << 16) | f2h(a.z);
        v.z = ((unsigned)f2h(b.y) << 16) | f2h(b.x);
        v.w = ((unsigned)f2h(b.w) << 16) | f2h(b.z);
        *(uint4*)(dst + (size_t)row * DDIM + ch * 64 + ((s ^ (row & 7)) << 3)) = v;
    }
}

// ---------------------------------------------------------------- ||e_k||^2 (exact fp32)
__global__ __launch_bounds__(256) void k_wsq(const float* __restrict__ W, float* __restrict__ wsq) {
    const int k = blockIdx.x;
    const int t = threadIdx.x;
    const float* w = W + (size_t)k * DDIM;
    const float a = w[t], b = w[t + 256], c = w[t + 512];
    float s = a * a + b * b + c * c;
    s = waveRedAdd(s);
    __shared__ float p[4];
    if ((t & 63) == 0) p[t >> 6] = s;
    __syncthreads();
    if (t == 0) wsq[k] = (p[0] + p[1]) + (p[2] + p[3]);
}

// ---------------------------------------------------------------- main GEMM (fp16 MFMA, gload_lds, 2-phase dbuf)
// 128x128 tile, BK2=64, DOUBLE-buffered LDS: issue STAGE(ch+1 -> buf^1) BEFORE computing
// buf[cur]; ONE __syncthreads() per chunk (its implicit vmcnt(0) drains the async loads).
// Load latency hides under the 32 MFMAs (guide T3-minimum pattern).
__global__ __launch_bounds__(256, 2) void k_partials_g(
    const ushort* __restrict__ Af16, const ushort* __restrict__ Wf16,
    const float* __restrict__ wsq,
    float* __restrict__ pm1, float* __restrict__ pm2, int* __restrict__ pidx)
{
    __shared__ __align__(16) ushort lds[2 * 2 * BM * BK2];   // [buf][A|W][128][64] fp16 = 64 KB

    // XCD-panel swizzle: each XCD owns a contiguous band of 64 row-panels, cb fastest.
    const int bid = blockIdx.x;
    const int rb = ((bid & 7) << 6) | (bid >> 6);
    const int cb = (bid >> 3) & 7;

    const int tid = threadIdx.x;
    const int wid = tid >> 6, lane = tid & 63;
    const int wr = wid >> 1, wc = wid & 1;       // wave quadrant (row-half, col-half)
    const int l15 = lane & 15, g = lane >> 4;    // frag row/col + k-group

    const ushort* Ab = Af16 + (size_t)rb * BM * DDIM;
    const ushort* Wb = Wf16 + (size_t)cb * BK * DDIM;

    const int srow = lane >> 3;     // row within an 8-row segment
    const int sslot = lane & 7;     // 16B slot within a 128B row-chunk

    f32x4 acc[4][4];
#pragma unroll
    for (int rt = 0; rt < 4; ++rt)
#pragma unroll
        for (int ct = 0; ct < 4; ++ct) acc[rt][ct] = (f32x4)0.f;

    auto STAGE = [&](int ch, int b) {
        ushort* As = lds + b * (2 * BM * BK2);
        ushort* Ws = As + BM * BK2;
#pragma unroll
        for (int i = 0; i < 4; ++i) {
            const int seg = (i << 2) | wid;                 // wave-uniform
            const int row = (seg << 3) | srow;              // 0..127
            GLOAD16(Ab + (size_t)row * DDIM + ch * BK2 + sslot * 8, (char*)As + (seg << 10));
            GLOAD16(Wb + (size_t)row * DDIM + ch * BK2 + sslot * 8, (char*)Ws + (seg << 10));
        }
    };

    STAGE(0, 0);
    __syncthreads();   // implicit vmcnt(0): buf0 staged

#pragma unroll 1
    for (int ch = 0; ch < NCH2; ++ch) {
        const int cur = ch & 1;
        if (ch + 1 < NCH2) STAGE(ch + 1, cur ^ 1);   // async; lands during compute
        const ushort* As = lds + cur * (2 * BM * BK2);
        const ushort* Ws = As + BM * BK2;
#pragma unroll
        for (int h = 0; h < 2; ++h) {   // two 16x16x32 k-halves of the 64-chunk
            half8 af[4], bf[4];
#pragma unroll
            for (int rt = 0; rt < 4; ++rt) {
                const int r = wr * 64 + rt * 16 + l15;
                af[rt] = *(const half8*)(As + r * BK2 + ((((h << 2) | g) ^ (r & 7)) << 3));
                const int c = wc * 64 + rt * 16 + l15;
                bf[rt] = *(const half8*)(Ws + c * BK2 + ((((h << 2) | g) ^ (c & 7)) << 3));
            }
#pragma unroll
            for (int rt = 0; rt < 4; ++rt)
#pragma unroll
                for (int ct = 0; ct < 4; ++ct)
                    acc[rt][ct] = __builtin_amdgcn_mfma_f32_16x16x32_f16(af[rt], bf[ct], acc[rt][ct], 0, 0, 0);
        }
        __syncthreads();   // drains vmcnt(0) -> next buf ready; cur buf free to overwrite
    }

    // ---------------- epilogue: per-row (min, 2nd-min, argmin) over this 128-code tile
    // C/D layout: col = lane&15, row = (lane>>4)*4 + q  [m89]
    float wq[4];
#pragma unroll
    for (int ct = 0; ct < 4; ++ct) wq[ct] = wsq[cb * BK + wc * 64 + ct * 16 + l15];
    const int cbase = cb * BK + wc * 64 + l15;

    float* tm1 = (float*)lds;          // [128][2]  (row-local, wc) — loop barrier already passed
    float* tm2 = tm1 + 256;
    int*   ti1 = (int*)(tm2 + 256);

#pragma unroll
    for (int rt = 0; rt < 4; ++rt) {
        float m1q[4], m2q[4]; int i1q[4];
#pragma unroll
        for (int q = 0; q < 4; ++q) { m1q[q] = INFINITY; m2q[q] = INFINITY; i1q[q] = 0x7fffffff; }
#pragma unroll
        for (int ct = 0; ct < 4; ++ct) {
            const int col = cbase + ct * 16;
#pragma unroll
            for (int q = 0; q < 4; ++q) {
                const float s = fmaf(-2.f, acc[rt][ct][q], wq[ct]);
                if (s < m1q[q]) { m2q[q] = m1q[q]; m1q[q] = s; i1q[q] = col; }
                else if (s < m2q[q]) m2q[q] = s;
            }
        }
#pragma unroll
        for (int msk = 1; msk <= 8; msk <<= 1) {
#pragma unroll
            for (int q = 0; q < 4; ++q) {
                const float om1 = __shfl_xor(m1q[q], msk);
                const float om2 = __shfl_xor(m2q[q], msk);
                const int   oi1 = __shfl_xor(i1q[q], msk);
                if (om1 < m1q[q] || (om1 == m1q[q] && oi1 < i1q[q])) {
                    m2q[q] = fminf(m1q[q], om2); m1q[q] = om1; i1q[q] = oi1;
                } else m2q[q] = fminf(m2q[q], om1);
            }
        }
        if (l15 == 0) {
#pragma unroll
            for (int q = 0; q < 4; ++q) {
                const int rl = wr * 64 + rt * 16 + g * 4 + q;   // row within block
                tm1[rl * 2 + wc] = m1q[q];
                tm2[rl * 2 + wc] = m2q[q];
                ti1[rl * 2 + wc] = i1q[q];
            }
        }
    }
    __syncthreads();
    if (tid < BM) {
        float m1 = tm1[tid * 2], m2 = tm2[tid * 2]; int i1 = ti1[tid * 2];
        const float bm1 = tm1[tid * 2 + 1], bm2 = tm2[tid * 2 + 1]; const int bi = ti1[tid * 2 + 1];
        if (bm1 < m1 || (bm1 == m1 && bi < i1)) { m2 = fminf(m1, bm2); m1 = bm1; i1 = bi; }
        else m2 = fminf(m2, bm1);
        const size_t row = (size_t)rb * BM + tid;
        pm1[row * NCB + cb] = m1;
        pm2[row * NCB + cb] = m2;
        pidx[row * NCB + cb] = i1;
    }
}

// ---------------------------------------------------------------- fallback GEMM (fused cvt) if ws too small
__global__ __launch_bounds__(256, 2) void k_partials(
    const float* __restrict__ A, const float* __restrict__ W,
    const float* __restrict__ wsq,
    float* __restrict__ pm1, float* __restrict__ pm2, int* __restrict__ pidx)
{
    __shared__ __align__(16) ushort lds[2 * BM * KC];
    ushort* As = lds;
    ushort* Ws = lds + BM * KC;

    const int bid = blockIdx.x;
    const int rb = ((bid & 7) << 6) | (bid >> 6);
    const int cb = (bid >> 3) & 7;

    const int tid = threadIdx.x;
    const int wid = tid >> 6, lane = tid & 63;
    const int wr = wid >> 1, wc = wid & 1;
    const int l15 = lane & 15, g = lane >> 4;

    const float* Ab = A + (size_t)rb * BM * DDIM;
    const float* Wb = W + (size_t)cb * BK * DDIM;

    const int srow = tid >> 3;
    const int sk4  = (tid & 7) << 2;
    const int sg   = (tid & 7) >> 1;
    const int sh   = (tid & 1) << 2;

    int aOff[4], bOff[4];
#pragma unroll
    for (int rt = 0; rt < 4; ++rt) {
        const int r = wr * 64 + rt * 16 + l15;
        aOff[rt] = r * KC + ((g ^ ((r >> 1) & 3)) << 3);
        const int c = wc * 64 + rt * 16 + l15;
        bOff[rt] = c * KC + ((g ^ ((c >> 1) & 3)) << 3);
    }

    f32x4 acc[4][4];
#pragma unroll
    for (int rt = 0; rt < 4; ++rt)
#pragma unroll
        for (int ct = 0; ct < 4; ++ct) acc[rt][ct] = (f32x4)0.f;

    float4 av[4], wv[4];
#pragma unroll
    for (int i = 0; i < 4; ++i) {
        av[i] = *(const float4*)(Ab + (size_t)(srow + 32 * i) * DDIM + sk4);
        wv[i] = *(const float4*)(Wb + (size_t)(srow + 32 * i) * DDIM + sk4);
    }

#pragma unroll 1
    for (int ch = 0; ch < NCH; ++ch) {
        __syncthreads();
#pragma unroll
        for (int i = 0; i < 4; ++i) {
            const int r = srow + 32 * i;
            const int wsl = r * KC + ((sg ^ ((r >> 1) & 3)) << 3) + sh;
            ushort4 ua; ua.x = f2h(av[i].x); ua.y = f2h(av[i].y); ua.z = f2h(av[i].z); ua.w = f2h(av[i].w);
            *(ushort4*)(As + wsl) = ua;
            ushort4 uw; uw.x = f2h(wv[i].x); uw.y = f2h(wv[i].y); uw.z = f2h(wv[i].z); uw.w = f2h(wv[i].w);
            *(ushort4*)(Ws + wsl) = uw;
        }
        __syncthreads();
        if (ch + 1 < NCH) {
            const int d0 = (ch + 1) * KC + sk4;
#pragma unroll
            for (int i = 0; i < 4; ++i) {
                av[i] = *(const float4*)(Ab + (size_t)(srow + 32 * i) * DDIM + d0);
                wv[i] = *(const float4*)(Wb + (size_t)(srow + 32 * i) * DDIM + d0);
            }
        }
        half8 af[4], bf[4];
#pragma unroll
        for (int rt = 0; rt < 4; ++rt) af[rt] = *(const half8*)(As + aOff[rt]);
#pragma unroll
        for (int ct = 0; ct < 4; ++ct) bf[ct] = *(const half8*)(Ws + bOff[ct]);
#pragma unroll
        for (int rt = 0; rt < 4; ++rt)
#pragma unroll
            for (int ct = 0; ct < 4; ++ct)
                acc[rt][ct] = __builtin_amdgcn_mfma_f32_16x16x32_f16(af[rt], bf[ct], acc[rt][ct], 0, 0, 0);
    }

    float wq[4];
#pragma unroll
    for (int ct = 0; ct < 4; ++ct) wq[ct] = wsq[cb * BK + wc * 64 + ct * 16 + l15];
    const int cbase = cb * BK + wc * 64 + l15;

    __syncthreads();
    float* tm1 = (float*)lds;
    float* tm2 = tm1 + 256;
    int*   ti1 = (int*)(tm2 + 256);

#pragma unroll
    for (int rt = 0; rt < 4; ++rt) {
        float m1q[4], m2q[4]; int i1q[4];
#pragma unroll
        for (int q = 0; q < 4; ++q) { m1q[q] = INFINITY; m2q[q] = INFINITY; i1q[q] = 0x7fffffff; }
#pragma unroll
        for (int ct = 0; ct < 4; ++ct) {
            const int col = cbase + ct * 16;
#pragma unroll
            for (int q = 0; q < 4; ++q) {
                const float s = fmaf(-2.f, acc[rt][ct][q], wq[ct]);
                if (s < m1q[q]) { m2q[q] = m1q[q]; m1q[q] = s; i1q[q] = col; }
                else if (s < m2q[q]) m2q[q] = s;
            }
        }
#pragma unroll
        for (int msk = 1; msk <= 8; msk <<= 1) {
#pragma unroll
            for (int q = 0; q < 4; ++q) {
                const float om1 = __shfl_xor(m1q[q], msk);
                const float om2 = __shfl_xor(m2q[q], msk);
                const int   oi1 = __shfl_xor(i1q[q], msk);
                if (om1 < m1q[q] || (om1 == m1q[q] && oi1 < i1q[q])) {
                    m2q[q] = fminf(m1q[q], om2); m1q[q] = om1; i1q[q] = oi1;
                } else m2q[q] = fminf(m2q[q], om1);
            }
        }
        if (l15 == 0) {
#pragma unroll
            for (int q = 0; q < 4; ++q) {
                const int rl = wr * 64 + rt * 16 + g * 4 + q;
                tm1[rl * 2 + wc] = m1q[q];
                tm2[rl * 2 + wc] = m2q[q];
                ti1[rl * 2 + wc] = i1q[q];
            }
        }
    }
    __syncthreads();
    if (tid < BM) {
        float m1 = tm1[tid * 2], m2 = tm2[tid * 2]; int i1 = ti1[tid * 2];
        const float bm1 = tm1[tid * 2 + 1], bm2 = tm2[tid * 2 + 1]; const int bi = ti1[tid * 2 + 1];
        if (bm1 < m1 || (bm1 == m1 && bi < i1)) { m2 = fminf(m1, bm2); m1 = bm1; i1 = bi; }
        else m2 = fminf(m2, bm1);
        const size_t row = (size_t)rb * BM + tid;
        pm1[row * NCB + cb] = m1;
        pm2[row * NCB + cb] = m2;
        pidx[row * NCB + cb] = i1;
    }
}

// ---------------------------------------------------------------- merge 8 partials per row
__global__ __launch_bounds__(256) void k_merge(
    const float* __restrict__ pm1, const float* __restrict__ pm2, const int* __restrict__ pidx,
    float* __restrict__ row_s, int* __restrict__ row_idx,
    int* __restrict__ suspects, int* __restrict__ n_suspect)
{
    const int row = blockIdx.x * 256 + threadIdx.x;
    float m1 = INFINITY, m2 = INFINITY; int i1 = 0x7fffffff;
#pragma unroll
    for (int cb = 0; cb < NCB; ++cb) {
        const float bm1 = pm1[(size_t)row * NCB + cb];
        const float bm2 = pm2[(size_t)row * NCB + cb];
        const int   bi  = pidx[(size_t)row * NCB + cb];
        if (bm1 < m1 || (bm1 == m1 && bi < i1)) { m2 = fminf(m1, bm2); m1 = bm1; i1 = bi; }
        else m2 = fminf(m2, bm1);
    }
    row_s[row] = m1;
    row_idx[row] = i1;
    if (m2 - m1 < GAP_TAU) {   // fp16 noise could have reordered: exact re-check
        const int p = atomicAdd(n_suspect, 1);
        suspects[p] = row;
    }
}

// ---------------------------------------------------------------- fp64 re-check of near-ties
// Block per suspect (grid-strided). Block-filter via pm1 (blocks within FILT_TAU of the
// global partial min; true winner provably inside). 4 lanes per code with interleaved
// 16B stripes: all 256 threads busy on 64 codes/round, dependent fp64 chain 4x shorter,
// conflict-free LDS (quad lanes hit consecutive banks; same-addr across quads broadcasts).
__global__ __launch_bounds__(256) void k_repair(
    const float* __restrict__ A, const float* __restrict__ W,
    const float* __restrict__ pm1,
    const int* __restrict__ suspects, const int* __restrict__ n_suspect,
    float* __restrict__ row_s, int* __restrict__ row_idx)
{
    __shared__ __align__(16) float xrow[DDIM];
    __shared__ double wbest[4]; __shared__ int wbi[4];
    __shared__ double xps[4];
    __shared__ int qcb[NCB];
    __shared__ int nq;
    const int ns = *n_suspect;
    const int tid = threadIdx.x;
    const int wid = tid >> 6, lane = tid & 63;
    const int sub = tid & 3;        // 16B stripe within a code
    const int cq  = tid >> 2;       // code slot 0..63

    for (int s = blockIdx.x; s < ns; s += gridDim.x) {
        const int row = suspects[s];
        __syncthreads();   // previous iteration done with shared
        xrow[tid]       = A[(size_t)row * DDIM + tid];
        xrow[tid + 256] = A[(size_t)row * DDIM + tid + 256];
        xrow[tid + 512] = A[(size_t)row * DDIM + tid + 512];
        if (tid == 0) {
            float gmin = INFINITY;
#pragma unroll
            for (int cb = 0; cb < NCB; ++cb) gmin = fminf(gmin, pm1[(size_t)row * NCB + cb]);
            int n = 0;
#pragma unroll
            for (int cb = 0; cb < NCB; ++cb)
                if (pm1[(size_t)row * NCB + cb] <= gmin + FILT_TAU) qcb[n++] = cb;
            nq = n;
        }
        __syncthreads();

        // xsq in fp64 (per-wave stripes combined at the end)
        double xp = 0.0;
        {
            double t;
            t = (double)xrow[tid];       xp = fma(t, t, xp);
            t = (double)xrow[tid + 256]; xp = fma(t, t, xp);
            t = (double)xrow[tid + 512]; xp = fma(t, t, xp);
        }
        xp = waveRedAdd(xp);
        if (lane == 0) xps[wid] = xp;

        double best = 1e300; int bi = 0x7fffffff;
        const int ncand = nq * BK;
        for (int base = 0; base < ncand; base += 64) {
            const int ci = base + cq;
            const bool act = ci < ncand;       // uniform within a quad
            double d = 0.0; int k = 0x7fffffff;
            if (act) {
                k = qcb[ci >> 7] * BK + (ci & (BK - 1));
                const float* wr = W + (size_t)k * DDIM + (sub << 2);
                const float* xr = xrow + (sub << 2);
                double d0 = 0.0, d1 = 0.0;
                for (int i = 0; i < DDIM; i += 16) {
                    const float4 wv = *(const float4*)(wr + i);
                    const float4 xv = *(const float4*)(xr + i);
                    double t;
                    t = (double)xv.x - (double)wv.x; d0 = fma(t, t, d0);
                    t = (double)xv.y - (double)wv.y; d1 = fma(t, t, d1);
                    t = (double)xv.z - (double)wv.z; d0 = fma(t, t, d0);
                    t = (double)xv.w - (double)wv.w; d1 = fma(t, t, d1);
                }
                d = d0 + d1;
            }
            d += __shfl_xor(d, 1);   // combine the 4 stripes of this code
            d += __shfl_xor(d, 2);
            if (act && sub == 0) {
                if (d < best || (d == best && k < bi)) { best = d; bi = k; }
            }
        }
        // wave butterfly (non-leaders hold +inf)
#pragma unroll
        for (int o = 32; o; o >>= 1) {
            const double ob = __shfl_xor(best, o);
            const int oi = __shfl_xor(bi, o);
            if (ob < best || (ob == best && oi < bi)) { best = ob; bi = oi; }
        }
        if (lane == 0) { wbest[wid] = best; wbi[wid] = bi; }
        __syncthreads();
        if (tid == 0) {
            double b = wbest[0]; int i1 = wbi[0];
#pragma unroll
            for (int w = 1; w < 4; ++w)
                if (wbest[w] < b || (wbest[w] == b && wbi[w] < i1)) { b = wbest[w]; i1 = wbi[w]; }
            row_idx[row] = i1;
            row_s[row] = (float)(b - (xps[0] + xps[1] + xps[2] + xps[3]));   // score form (dist - xsq)
        }
    }
}

// ---------------------------------------------------------------- quantize + losses + idx/min_d outputs
__global__ __launch_bounds__(256) void k_quantize(
    const float* __restrict__ A, const float* __restrict__ W,
    const float* __restrict__ row_s, const int* __restrict__ row_idx,
    float* __restrict__ out, float* __restrict__ counts,
    unsigned int* __restrict__ n_valid, double* __restrict__ sum_sqerr)
{
    const int wid = threadIdx.x >> 6, lane = threadIdx.x & 63;
    __shared__ double s_sum[4];
    __shared__ unsigned s_val[4];
    double wsum = 0.0; unsigned wval = 0;

#pragma unroll 1
    for (int it = 0; it < NROWS / (QGRID * 4); ++it) {
        const int row = (it * QGRID + blockIdx.x) * 4 + wid;
        const float* x = A + (size_t)row * DDIM;
        float4 xv[3];
#pragma unroll
        for (int j = 0; j < 3; ++j) xv[j] = *(const float4*)(x + (lane + 64 * j) * 4);
        float xsq = 0.f;
#pragma unroll
        for (int j = 0; j < 3; ++j)
            xsq += xv[j].x * xv[j].x + xv[j].y * xv[j].y + xv[j].z * xv[j].z + xv[j].w * xv[j].w;
        xsq = waveRedAdd(xsq);
        const bool valid = xsq > 1e-12f;            // norm > 1e-6
        const float maskf = valid ? 1.f : 0.f;
        const int idx = row_idx[row];
        const int idxm = valid ? idx : 0;
        const float* w = W + (size_t)idx * DDIM;
        float* oq = out + (size_t)row * DDIM;
        float e2 = 0.f;
#pragma unroll
        for (int j = 0; j < 3; ++j) {
            const float4 wvv = *(const float4*)(w + (lane + 64 * j) * 4);
            const float xs[4] = {xv[j].x, xv[j].y, xv[j].z, xv[j].w};
            const float ws[4] = {wvv.x, wvv.y, wvv.z, wvv.w};
            float os[4];
#pragma unroll
            for (int c = 0; c < 4; ++c) {
                const float q = ws[c] * maskf;          // q_flat = weight[idx] * mask
                os[c] = xs[c] + (q - xs[c]);            // quantized_st
                const float d = xs[c] - q;
                e2 += d * d;
            }
            float4 ov; ov.x = os[0]; ov.y = os[1]; ov.z = os[2]; ov.w = os[3];
            *(float4*)(oq + (lane + 64 * j) * 4) = ov;
        }
        e2 = waveRedAdd(e2);
        if (lane == 0) {
            wsum += (double)(maskf * e2);
            if (valid) {
                ++wval;
                atomicAdd(&counts[idxm], 1.0f);
            }
            out[OUT_IDX + row]  = (float)idxm;
            out[OUT_MIND + row] = valid ? (xsq + row_s[row]) : 0.f;
        }
    }

    if (lane == 0) { s_sum[wid] = wsum; s_val[wid] = wval; }
    __syncthreads();
    if (threadIdx.x == 0) {
        atomicAdd(sum_sqerr, s_sum[0] + s_sum[1] + s_sum[2] + s_sum[3]);
        atomicAdd(n_valid, s_val[0] + s_val[1] + s_val[2] + s_val[3]);
    }
}

// ---------------------------------------------------------------- scalar losses
__global__ __launch_bounds__(256) void k_final(
    const float* __restrict__ counts, const unsigned int* __restrict__ n_valid,
    const double* __restrict__ sum_sqerr, float* __restrict__ out)
{
    const int t = threadIdx.x;
    const float nv = (float)(*n_valid);
    double ent = 0.0;
    for (int k = t; k < KCODES; k += 256) {
        const float p = counts[k] / nv;
        ent += (double)(p * logf(p + 1e-10f));
    }
    ent = waveRedAdd(ent);
    __shared__ double ps[4];
    if ((t & 63) == 0) ps[t >> 6] = ent;
    __syncthreads();
    if (t == 0) {
        const double e = ps[0] + ps[1] + ps[2] + ps[3];
        const double perp = exp(-e);
        const double ploss = -log(perp + 1e-10);
        const double commit = *sum_sqerr / ((double)(*n_valid) * (double)DDIM);
        out[OUT_LOSS] = (float)(0.25 * commit + 0.1 * ploss);
        out[OUT_PERP] = (float)perp;
    }
}

// ----------------------------------------------------------------
extern "C" void kernel_launch(void* const* d_in, const int* in_sizes, int n_in,
                              void* d_out, int out_size, void* d_ws, size_t ws_size,
                              hipStream_t stream) {
    const float* A = (const float*)d_in[0];   // [65536, 768]
    const float* W = (const float*)d_in[1];   // [1024, 768]
    float* out = (float*)d_out;
    char* ws = (char*)d_ws;
    if (ws_size < (size_t)WS_END) return;     // needs >=6.8 MB scratch

    double*   sum_sqerr = (double*)(ws + WS_SUM);
    int*      n_suspect = (int*)(ws + WS_NSUS);
    unsigned* n_valid   = (unsigned*)(ws + WS_NVAL);
    float*    counts    = (float*)(ws + WS_COUNTS);
    float*    wsq       = (float*)(ws + WS_WSQ);
    float*    row_s     = (float*)(ws + WS_ROWS);
    int*      row_idx   = (int*)(ws + WS_ROWI);
    int*      suspects  = (int*)(ws + WS_SUSP);
    float*    pm1       = (float*)(ws + WS_PM1);
    float*    pm2       = (float*)(ws + WS_PM2);
    int*      pidx      = (int*)(ws + WS_PIDX);
    ushort*   Af16      = (ushort*)(ws + WS_AF16);
    ushort*   Wf16      = (ushort*)(ws + WS_WF16);

    const bool big = ws_size >= (size_t)WS_END2;   // ~105 MB: fp16-preconvert path

    hipLaunchKernelGGL(k_init, dim3(1), dim3(256), 0, stream, counts, n_suspect, n_valid, sum_sqerr);
    if (big)
        hipLaunchKernelGGL(k_convert, dim3(2048), dim3(256), 0, stream, A, W, Af16, Wf16);
    hipLaunchKernelGGL(k_wsq, dim3(KCODES), dim3(256), 0, stream, W, wsq);
    if (big)
        hipLaunchKernelGGL(k_partials_g, dim3((NROWS / BM) * NCB), dim3(256), 0, stream, Af16, Wf16, wsq, pm1, pm2, pidx);
    else
        hipLaunchKernelGGL(k_partials, dim3((NROWS / BM) * NCB), dim3(256), 0, stream, A, W, wsq, pm1, pm2, pidx);
    hipLaunchKernelGGL(k_merge, dim3(NROWS / 256), dim3(256), 0, stream, pm1, pm2, pidx, row_s, row_idx, suspects, n_suspect);
    hipLaunchKernelGGL(k_repair, dim3(RGRID), dim3(256), 0, stream, A, W, pm1, suspects, n_suspect, row_s, row_idx);
    hipLaunchKernelGGL(k_quantize, dim3(QGRID), dim3(256), 0, stream, A, W, row_s, row_idx, out, counts, n_valid, sum_sqerr);
    hipLaunchKernelGGL(k_final, dim3(1), dim3(256), 0, stream, counts, n_valid, sum_sqerr, out);
}

// Round 8
// 368.012 us; speedup vs baseline: 18.1325x; 1.0964x over previous
//
#include <hip/hip_runtime.h>
#include <hip/hip_bf16.h>
#include <math.h>

// Problem constants
#define NROWS 65536      // 32*2048
#define DDIM  768
#define KCODES 1024
#define NCB   8          // code blocks (KCODES / BK)
#define BM    128        // rows per block tile
#define BK    128        // codes per block tile
#define KC    32         // K-chunk for fallback kernel
#define NCH   (DDIM / KC)
#define BK2   32         // K-chunk (fp16) for gload_lds kernel (was 64; 32 -> 4 blocks/CU)
#define NCH2  (DDIM / BK2)
#define GAP_TAU  0.3f    // fp16 score-error guard band (~7.5 sigma); near-ties re-checked in fp64
#define FILT_TAU 0.6f    // repair block-filter margin (2x guard band)
#define RGRID 2048       // k_repair blocks
#define QGRID 2048       // k_quantize blocks

// ---- output offsets (d_out is float32, outputs concatenated in return order)
#define OUT_LOSS ((size_t)NROWS * DDIM)
#define OUT_IDX  (OUT_LOSS + 1)
#define OUT_MIND (OUT_IDX + NROWS)
#define OUT_PERP (OUT_MIND + NROWS)

// ---- workspace offsets (bytes)
#define WS_SUM    0                              // double sum_sqerr
#define WS_NSUS   8                              // int n_suspect
#define WS_NVAL   12                             // unsigned n_valid
#define WS_COUNTS 256                            // float[KCODES]
#define WS_WSQ    (WS_COUNTS + 4*KCODES)         // float[KCODES]
#define WS_ROWS   (WS_WSQ + 4*KCODES)            // float[NROWS] row min score (dist - xsq)
#define WS_ROWI   (WS_ROWS + 4*NROWS)            // int[NROWS] row argmin
#define WS_SUSP   (WS_ROWI + 4*NROWS)            // int[NROWS] suspect rows
#define WS_PM1    (WS_SUSP + 4*NROWS)            // float[NROWS*NCB] partial min
#define WS_PM2    (WS_PM1 + (size_t)4*NROWS*NCB) // float[NROWS*NCB] partial 2nd min
#define WS_PIDX   (WS_PM2 + (size_t)4*NROWS*NCB) // int[NROWS*NCB] partial argmin
#define WS_END    (WS_PIDX + (size_t)4*NROWS*NCB)
// fp16 mirrors (pre-swizzled), used only if ws_size permits (~105 MB total)
#define WS_AF16   ((WS_END + 255) & ~(size_t)255)
#define WS_WF16   (WS_AF16 + (size_t)NROWS * DDIM * 2)
#define WS_END2   (WS_WF16 + (size_t)KCODES * DDIM * 2)

typedef __attribute__((ext_vector_type(8))) _Float16 half8;  // 8 f16 = 4 VGPRs (MFMA A/B frag)
typedef __attribute__((ext_vector_type(4))) float f32x4;     // MFMA C/D frag

// async global->LDS, 16B per lane; LDS dest = wave-uniform base + lane*16
#define GLOAD16(gsrc, ldst) \
    __builtin_amdgcn_global_load_lds( \
        (const __attribute__((address_space(1))) unsigned int*)(gsrc), \
        (__attribute__((address_space(3))) unsigned int*)(ldst), 16, 0, 0)

template <typename T>
__device__ inline T waveRedAdd(T v) {
#pragma unroll
    for (int o = 32; o; o >>= 1) v += __shfl_xor(v, o);
    return v;
}

__device__ inline ushort f2h(float f) {
    union { _Float16 h; ushort u; } c;
    c.h = (_Float16)f;   // RTN-even
    return c.u;
}

// ---------------------------------------------------------------- init
__global__ void k_init(float* counts, int* n_suspect, unsigned* n_valid, double* sum_sqerr) {
    const int t = threadIdx.x;
    if (t == 0) { *n_suspect = 0; *n_valid = 0u; *sum_sqerr = 0.0; }
    for (int k = t; k < KCODES; k += 256) counts[k] = 0.f;
}

// ---------------------------------------------------------------- fp32 -> fp16 pre-convert (slot-swizzled)
// Row layout: 24 chunks of 32 fp16 (64 B); each chunk = 4 slots of 16B; slot s stored
// at s ^ ((row>>1)&3). With row stride 64 B, a ds_read_b128 by 16 consecutive rows then
// hits each bank-quad exactly 2x (2-way = free, m136). Linear global_load_lds staging
// mirrors this layout bit-for-bit (rule #21 / m173).
#define ASLOTS (NROWS * (DDIM / 8))
#define TSLOTS ((NROWS + KCODES) * (DDIM / 8))
__global__ __launch_bounds__(256) void k_convert(
    const float* __restrict__ A, const float* __restrict__ W,
    ushort* __restrict__ Af16, ushort* __restrict__ Wf16)
{
    for (int gidx = blockIdx.x * 256 + threadIdx.x; gidx < TSLOTS; gidx += gridDim.x * 256) {
        const float* src; ushort* dst; int sid;
        if (gidx < ASLOTS) { src = A; dst = Af16; sid = gidx; }
        else { src = W; dst = Wf16; sid = gidx - ASLOTS; }
        const int row = sid / 96;           // 96 slots per row
        const int sl = sid - row * 96;
        const int ch = sl >> 2, s = sl & 3; // 24 chunks x 4 slots
        const float* p = src + (size_t)row * DDIM + ch * 32 + s * 8;
        const float4 a = *(const float4*)p;
        const float4 b = *(const float4*)(p + 4);
        uint4 v;
        v.x = ((unsigned)f2h(a.y) << 16) | f2h(a.x);
        v.y = ((unsigned)f2h(a.w) << 16) | f2h(a.z);
        v.z = ((unsigned)f2h(b.y) << 16) | f2h(b.x);
        v.w = ((unsigned)f2h(b.w) << 16) | f2h(b.z);
        *(uint4*)(dst + (size_t)row * DDIM + ch * 32 + ((s ^ ((row >> 1) & 3)) << 3)) = v;
    }
}

// ---------------------------------------------------------------- ||e_k||^2 (exact fp32)
__global__ __launch_bounds__(256) void k_wsq(const float* __restrict__ W, float* __restrict__ wsq) {
    const int k = blockIdx.x;
    const int t = threadIdx.x;
    const float* w = W + (size_t)k * DDIM;
    const float a = w[t], b = w[t + 256], c = w[t + 512];
    float s = a * a + b * b + c * c;
    s = waveRedAdd(s);
    __shared__ float p[4];
    if ((t & 63) == 0) p[t >> 6] = s;
    __syncthreads();
    if (t == 0) wsq[k] = (p[0] + p[1]) + (p[2] + p[3]);
}

// ---------------------------------------------------------------- main GEMM (fp16 MFMA, gload_lds, dbuf, 4 blocks/CU)
// 128x128 tile, BK2=32, double-buffered 32 KB LDS -> 4 blocks/CU resident: while one
// block drains vmcnt(0) at its barrier, the other 3 blocks' waves feed MFMA/LDS (m114
// implicit overlap). STAGE(ch+1) issued before compute(ch); ONE barrier per chunk.
__global__ __launch_bounds__(256, 4) void k_partials_g(
    const ushort* __restrict__ Af16, const ushort* __restrict__ Wf16,
    const float* __restrict__ wsq,
    float* __restrict__ pm1, float* __restrict__ pm2, int* __restrict__ pidx)
{
    __shared__ __align__(16) ushort lds[2 * 2 * BM * BK2];   // [buf][A|W][128][32] fp16 = 32 KB

    // XCD-panel swizzle: each XCD owns a contiguous band of 64 row-panels, cb fastest.
    const int bid = blockIdx.x;
    const int rb = ((bid & 7) << 6) | (bid >> 6);
    const int cb = (bid >> 3) & 7;

    const int tid = threadIdx.x;
    const int wid = tid >> 6, lane = tid & 63;
    const int wr = wid >> 1, wc = wid & 1;       // wave quadrant (row-half, col-half)
    const int l15 = lane & 15, g = lane >> 4;    // frag row/col + k-group (0..3, 8 f16 each)

    const ushort* Ab = Af16 + (size_t)rb * BM * DDIM;
    const ushort* Wb = Wf16 + (size_t)cb * BK * DDIM;

    const int srow = lane >> 2;     // row within a 16-row segment
    const int sslot = lane & 3;     // 16B slot within a 64B row-chunk

    f32x4 acc[4][4];
#pragma unroll
    for (int rt = 0; rt < 4; ++rt)
#pragma unroll
        for (int ct = 0; ct < 4; ++ct) acc[rt][ct] = (f32x4)0.f;

    auto STAGE = [&](int ch, int b) {
        ushort* As = lds + b * (2 * BM * BK2);
        ushort* Ws = As + BM * BK2;
#pragma unroll
        for (int i = 0; i < 2; ++i) {
            const int seg = (i << 2) | wid;                 // wave-uniform, 0..7
            const int row = (seg << 4) | srow;              // 0..127
            GLOAD16(Ab + (size_t)row * DDIM + ch * BK2 + sslot * 8, (char*)As + (seg << 10));
            GLOAD16(Wb + (size_t)row * DDIM + ch * BK2 + sslot * 8, (char*)Ws + (seg << 10));
        }
    };

    STAGE(0, 0);
    __syncthreads();   // implicit vmcnt(0): buf0 staged

#pragma unroll 1
    for (int ch = 0; ch < NCH2; ++ch) {
        const int cur = ch & 1;
        if (ch + 1 < NCH2) STAGE(ch + 1, cur ^ 1);   // async; lands during compute + other blocks
        const ushort* As = lds + cur * (2 * BM * BK2);
        const ushort* Ws = As + BM * BK2;
        half8 bf[4];
#pragma unroll
        for (int ct = 0; ct < 4; ++ct) {
            const int c = wc * 64 + ct * 16 + l15;
            bf[ct] = *(const half8*)(Ws + c * BK2 + ((g ^ ((c >> 1) & 3)) << 3));
        }
#pragma unroll
        for (int rt = 0; rt < 4; ++rt) {
            const int r = wr * 64 + rt * 16 + l15;
            const half8 af = *(const half8*)(As + r * BK2 + ((g ^ ((r >> 1) & 3)) << 3));
#pragma unroll
            for (int ct = 0; ct < 4; ++ct)
                acc[rt][ct] = __builtin_amdgcn_mfma_f32_16x16x32_f16(af, bf[ct], acc[rt][ct], 0, 0, 0);
        }
        __syncthreads();   // drains vmcnt(0) -> next buf ready; cur buf free to overwrite
    }

    // ---------------- epilogue: per-row (min, 2nd-min, argmin) over this 128-code tile
    // C/D layout: col = lane&15, row = (lane>>4)*4 + q  [m89]
    float wq[4];
#pragma unroll
    for (int ct = 0; ct < 4; ++ct) wq[ct] = wsq[cb * BK + wc * 64 + ct * 16 + l15];
    const int cbase = cb * BK + wc * 64 + l15;

    float* tm1 = (float*)lds;          // [128][2]  (row-local, wc) — loop barrier already passed
    float* tm2 = tm1 + 256;
    int*   ti1 = (int*)(tm2 + 256);

#pragma unroll
    for (int rt = 0; rt < 4; ++rt) {
        float m1q[4], m2q[4]; int i1q[4];
#pragma unroll
        for (int q = 0; q < 4; ++q) { m1q[q] = INFINITY; m2q[q] = INFINITY; i1q[q] = 0x7fffffff; }
#pragma unroll
        for (int ct = 0; ct < 4; ++ct) {
            const int col = cbase + ct * 16;
#pragma unroll
            for (int q = 0; q < 4; ++q) {
                const float s = fmaf(-2.f, acc[rt][ct][q], wq[ct]);
                if (s < m1q[q]) { m2q[q] = m1q[q]; m1q[q] = s; i1q[q] = col; }
                else if (s < m2q[q]) m2q[q] = s;
            }
        }
#pragma unroll
        for (int msk = 1; msk <= 8; msk <<= 1) {
#pragma unroll
            for (int q = 0; q < 4; ++q) {
                const float om1 = __shfl_xor(m1q[q], msk);
                const float om2 = __shfl_xor(m2q[q], msk);
                const int   oi1 = __shfl_xor(i1q[q], msk);
                if (om1 < m1q[q] || (om1 == m1q[q] && oi1 < i1q[q])) {
                    m2q[q] = fminf(m1q[q], om2); m1q[q] = om1; i1q[q] = oi1;
                } else m2q[q] = fminf(m2q[q], om1);
            }
        }
        if (l15 == 0) {
#pragma unroll
            for (int q = 0; q < 4; ++q) {
                const int rl = wr * 64 + rt * 16 + g * 4 + q;   // row within block
                tm1[rl * 2 + wc] = m1q[q];
                tm2[rl * 2 + wc] = m2q[q];
                ti1[rl * 2 + wc] = i1q[q];
            }
        }
    }
    __syncthreads();
    if (tid < BM) {
        float m1 = tm1[tid * 2], m2 = tm2[tid * 2]; int i1 = ti1[tid * 2];
        const float bm1 = tm1[tid * 2 + 1], bm2 = tm2[tid * 2 + 1]; const int bi = ti1[tid * 2 + 1];
        if (bm1 < m1 || (bm1 == m1 && bi < i1)) { m2 = fminf(m1, bm2); m1 = bm1; i1 = bi; }
        else m2 = fminf(m2, bm1);
        const size_t row = (size_t)rb * BM + tid;
        pm1[row * NCB + cb] = m1;
        pm2[row * NCB + cb] = m2;
        pidx[row * NCB + cb] = i1;
    }
}

// ---------------------------------------------------------------- fallback GEMM (fused cvt) if ws too small
__global__ __launch_bounds__(256, 2) void k_partials(
    const float* __restrict__ A, const float* __restrict__ W,
    const float* __restrict__ wsq,
    float* __restrict__ pm1, float* __restrict__ pm2, int* __restrict__ pidx)
{
    __shared__ __align__(16) ushort lds[2 * BM * KC];
    ushort* As = lds;
    ushort* Ws = lds + BM * KC;

    const int bid = blockIdx.x;
    const int rb = ((bid & 7) << 6) | (bid >> 6);
    const int cb = (bid >> 3) & 7;

    const int tid = threadIdx.x;
    const int wid = tid >> 6, lane = tid & 63;
    const int wr = wid >> 1, wc = wid & 1;
    const int l15 = lane & 15, g = lane >> 4;

    const float* Ab = A + (size_t)rb * BM * DDIM;
    const float* Wb = W + (size_t)cb * BK * DDIM;

    const int srow = tid >> 3;
    const int sk4  = (tid & 7) << 2;
    const int sg   = (tid & 7) >> 1;
    const int sh   = (tid & 1) << 2;

    int aOff[4], bOff[4];
#pragma unroll
    for (int rt = 0; rt < 4; ++rt) {
        const int r = wr * 64 + rt * 16 + l15;
        aOff[rt] = r * KC + ((g ^ ((r >> 1) & 3)) << 3);
        const int c = wc * 64 + rt * 16 + l15;
        bOff[rt] = c * KC + ((g ^ ((c >> 1) & 3)) << 3);
    }

    f32x4 acc[4][4];
#pragma unroll
    for (int rt = 0; rt < 4; ++rt)
#pragma unroll
        for (int ct = 0; ct < 4; ++ct) acc[rt][ct] = (f32x4)0.f;

    float4 av[4], wv[4];
#pragma unroll
    for (int i = 0; i < 4; ++i) {
        av[i] = *(const float4*)(Ab + (size_t)(srow + 32 * i) * DDIM + sk4);
        wv[i] = *(const float4*)(Wb + (size_t)(srow + 32 * i) * DDIM + sk4);
    }

#pragma unroll 1
    for (int ch = 0; ch < NCH; ++ch) {
        __syncthreads();
#pragma unroll
        for (int i = 0; i < 4; ++i) {
            const int r = srow + 32 * i;
            const int wsl = r * KC + ((sg ^ ((r >> 1) & 3)) << 3) + sh;
            ushort4 ua; ua.x = f2h(av[i].x); ua.y = f2h(av[i].y); ua.z = f2h(av[i].z); ua.w = f2h(av[i].w);
            *(ushort4*)(As + wsl) = ua;
            ushort4 uw; uw.x = f2h(wv[i].x); uw.y = f2h(wv[i].y); uw.z = f2h(wv[i].z); uw.w = f2h(wv[i].w);
            *(ushort4*)(Ws + wsl) = uw;
        }
        __syncthreads();
        if (ch + 1 < NCH) {
            const int d0 = (ch + 1) * KC + sk4;
#pragma unroll
            for (int i = 0; i < 4; ++i) {
                av[i] = *(const float4*)(Ab + (size_t)(srow + 32 * i) * DDIM + d0);
                wv[i] = *(const float4*)(Wb + (size_t)(srow + 32 * i) * DDIM + d0);
            }
        }
        half8 af[4], bf[4];
#pragma unroll
        for (int rt = 0; rt < 4; ++rt) af[rt] = *(const half8*)(As + aOff[rt]);
#pragma unroll
        for (int ct = 0; ct < 4; ++ct) bf[ct] = *(const half8*)(Ws + bOff[ct]);
#pragma unroll
        for (int rt = 0; rt < 4; ++rt)
#pragma unroll
            for (int ct = 0; ct < 4; ++ct)
                acc[rt][ct] = __builtin_amdgcn_mfma_f32_16x16x32_f16(af[rt], bf[ct], acc[rt][ct], 0, 0, 0);
    }

    float wq[4];
#pragma unroll
    for (int ct = 0; ct < 4; ++ct) wq[ct] = wsq[cb * BK + wc * 64 + ct * 16 + l15];
    const int cbase = cb * BK + wc * 64 + l15;

    __syncthreads();
    float* tm1 = (float*)lds;
    float* tm2 = tm1 + 256;
    int*   ti1 = (int*)(tm2 + 256);

#pragma unroll
    for (int rt = 0; rt < 4; ++rt) {
        float m1q[4], m2q[4]; int i1q[4];
#pragma unroll
        for (int q = 0; q < 4; ++q) { m1q[q] = INFINITY; m2q[q] = INFINITY; i1q[q] = 0x7fffffff; }
#pragma unroll
        for (int ct = 0; ct < 4; ++ct) {
            const int col = cbase + ct * 16;
#pragma unroll
            for (int q = 0; q < 4; ++q) {
                const float s = fmaf(-2.f, acc[rt][ct][q], wq[ct]);
                if (s < m1q[q]) { m2q[q] = m1q[q]; m1q[q] = s; i1q[q] = col; }
                else if (s < m2q[q]) m2q[q] = s;
            }
        }
#pragma unroll
        for (int msk = 1; msk <= 8; msk <<= 1) {
#pragma unroll
            for (int q = 0; q < 4; ++q) {
                const float om1 = __shfl_xor(m1q[q], msk);
                const float om2 = __shfl_xor(m2q[q], msk);
                const int   oi1 = __shfl_xor(i1q[q], msk);
                if (om1 < m1q[q] || (om1 == m1q[q] && oi1 < i1q[q])) {
                    m2q[q] = fminf(m1q[q], om2); m1q[q] = om1; i1q[q] = oi1;
                } else m2q[q] = fminf(m2q[q], om1);
            }
        }
        if (l15 == 0) {
#pragma unroll
            for (int q = 0; q < 4; ++q) {
                const int rl = wr * 64 + rt * 16 + g * 4 + q;
                tm1[rl * 2 + wc] = m1q[q];
                tm2[rl * 2 + wc] = m2q[q];
                ti1[rl * 2 + wc] = i1q[q];
            }
        }
    }
    __syncthreads();
    if (tid < BM) {
        float m1 = tm1[tid * 2], m2 = tm2[tid * 2]; int i1 = ti1[tid * 2];
        const float bm1 = tm1[tid * 2 + 1], bm2 = tm2[tid * 2 + 1]; const int bi = ti1[tid * 2 + 1];
        if (bm1 < m1 || (bm1 == m1 && bi < i1)) { m2 = fminf(m1, bm2); m1 = bm1; i1 = bi; }
        else m2 = fminf(m2, bm1);
        const size_t row = (size_t)rb * BM + tid;
        pm1[row * NCB + cb] = m1;
        pm2[row * NCB + cb] = m2;
        pidx[row * NCB + cb] = i1;
    }
}

// ---------------------------------------------------------------- merge 8 partials per row
__global__ __launch_bounds__(256) void k_merge(
    const float* __restrict__ pm1, const float* __restrict__ pm2, const int* __restrict__ pidx,
    float* __restrict__ row_s, int* __restrict__ row_idx,
    int* __restrict__ suspects, int* __restrict__ n_suspect)
{
    const int row = blockIdx.x * 256 + threadIdx.x;
    float m1 = INFINITY, m2 = INFINITY; int i1 = 0x7fffffff;
#pragma unroll
    for (int cb = 0; cb < NCB; ++cb) {
        const float bm1 = pm1[(size_t)row * NCB + cb];
        const float bm2 = pm2[(size_t)row * NCB + cb];
        const int   bi  = pidx[(size_t)row * NCB + cb];
        if (bm1 < m1 || (bm1 == m1 && bi < i1)) { m2 = fminf(m1, bm2); m1 = bm1; i1 = bi; }
        else m2 = fminf(m2, bm1);
    }
    row_s[row] = m1;
    row_idx[row] = i1;
    if (m2 - m1 < GAP_TAU) {   // fp16 noise could have reordered: exact re-check
        const int p = atomicAdd(n_suspect, 1);
        suspects[p] = row;
    }
}

// ---------------------------------------------------------------- fp64 re-check of near-ties
// Block per suspect (grid-strided). Block-filter via pm1 (blocks within FILT_TAU of the
// global partial min; true winner provably inside). 4 lanes per code with interleaved
// 16B stripes: all 256 threads busy on 64 codes/round, dependent fp64 chain 4x shorter.
__global__ __launch_bounds__(256) void k_repair(
    const float* __restrict__ A, const float* __restrict__ W,
    const float* __restrict__ pm1,
    const int* __restrict__ suspects, const int* __restrict__ n_suspect,
    float* __restrict__ row_s, int* __restrict__ row_idx)
{
    __shared__ __align__(16) float xrow[DDIM];
    __shared__ double wbest[4]; __shared__ int wbi[4];
    __shared__ double xps[4];
    __shared__ int qcb[NCB];
    __shared__ int nq;
    const int ns = *n_suspect;
    const int tid = threadIdx.x;
    const int wid = tid >> 6, lane = tid & 63;
    const int sub = tid & 3;        // 16B stripe within a code
    const int cq  = tid >> 2;       // code slot 0..63

    for (int s = blockIdx.x; s < ns; s += gridDim.x) {
        const int row = suspects[s];
        __syncthreads();   // previous iteration done with shared
        xrow[tid]       = A[(size_t)row * DDIM + tid];
        xrow[tid + 256] = A[(size_t)row * DDIM + tid + 256];
        xrow[tid + 512] = A[(size_t)row * DDIM + tid + 512];
        if (tid == 0) {
            float gmin = INFINITY;
#pragma unroll
            for (int cb = 0; cb < NCB; ++cb) gmin = fminf(gmin, pm1[(size_t)row * NCB + cb]);
            int n = 0;
#pragma unroll
            for (int cb = 0; cb < NCB; ++cb)
                if (pm1[(size_t)row * NCB + cb] <= gmin + FILT_TAU) qcb[n++] = cb;
            nq = n;
        }
        __syncthreads();

        // xsq in fp64 (per-wave stripes combined at the end)
        double xp = 0.0;
        {
            double t;
            t = (double)xrow[tid];       xp = fma(t, t, xp);
            t = (double)xrow[tid + 256]; xp = fma(t, t, xp);
            t = (double)xrow[tid + 512]; xp = fma(t, t, xp);
        }
        xp = waveRedAdd(xp);
        if (lane == 0) xps[wid] = xp;

        double best = 1e300; int bi = 0x7fffffff;
        const int ncand = nq * BK;
        for (int base = 0; base < ncand; base += 64) {
            const int ci = base + cq;
            const bool act = ci < ncand;       // uniform within a quad
            double d = 0.0; int k = 0x7fffffff;
            if (act) {
                k = qcb[ci >> 7] * BK + (ci & (BK - 1));
                const float* wr = W + (size_t)k * DDIM + (sub << 2);
                const float* xr = xrow + (sub << 2);
                double d0 = 0.0, d1 = 0.0;
                for (int i = 0; i < DDIM; i += 16) {
                    const float4 wv = *(const float4*)(wr + i);
                    const float4 xv = *(const float4*)(xr + i);
                    double t;
                    t = (double)xv.x - (double)wv.x; d0 = fma(t, t, d0);
                    t = (double)xv.y - (double)wv.y; d1 = fma(t, t, d1);
                    t = (double)xv.z - (double)wv.z; d0 = fma(t, t, d0);
                    t = (double)xv.w - (double)wv.w; d1 = fma(t, t, d1);
                }
                d = d0 + d1;
            }
            d += __shfl_xor(d, 1);   // combine the 4 stripes of this code
            d += __shfl_xor(d, 2);
            if (act && sub == 0) {
                if (d < best || (d == best && k < bi)) { best = d; bi = k; }
            }
        }
        // wave butterfly (non-leaders hold +inf)
#pragma unroll
        for (int o = 32; o; o >>= 1) {
            const double ob = __shfl_xor(best, o);
            const int oi = __shfl_xor(bi, o);
            if (ob < best || (ob == best && oi < bi)) { best = ob; bi = oi; }
        }
        if (lane == 0) { wbest[wid] = best; wbi[wid] = bi; }
        __syncthreads();
        if (tid == 0) {
            double b = wbest[0]; int i1 = wbi[0];
#pragma unroll
            for (int w = 1; w < 4; ++w)
                if (wbest[w] < b || (wbest[w] == b && wbi[w] < i1)) { b = wbest[w]; i1 = wbi[w]; }
            row_idx[row] = i1;
            row_s[row] = (float)(b - (xps[0] + xps[1] + xps[2] + xps[3]));   // score form (dist - xsq)
        }
    }
}

// ---------------------------------------------------------------- quantize + losses + idx/min_d outputs
__global__ __launch_bounds__(256) void k_quantize(
    const float* __restrict__ A, const float* __restrict__ W,
    const float* __restrict__ row_s, const int* __restrict__ row_idx,
    float* __restrict__ out, float* __restrict__ counts,
    unsigned int* __restrict__ n_valid, double* __restrict__ sum_sqerr)
{
    const int wid = threadIdx.x >> 6, lane = threadIdx.x & 63;
    __shared__ double s_sum[4];
    __shared__ unsigned s_val[4];
    double wsum = 0.0; unsigned wval = 0;

#pragma unroll 1
    for (int it = 0; it < NROWS / (QGRID * 4); ++it) {
        const int row = (it * QGRID + blockIdx.x) * 4 + wid;
        const float* x = A + (size_t)row * DDIM;
        float4 xv[3];
#pragma unroll
        for (int j = 0; j < 3; ++j) xv[j] = *(const float4*)(x + (lane + 64 * j) * 4);
        float xsq = 0.f;
#pragma unroll
        for (int j = 0; j < 3; ++j)
            xsq += xv[j].x * xv[j].x + xv[j].y * xv[j].y + xv[j].z * xv[j].z + xv[j].w * xv[j].w;
        xsq = waveRedAdd(xsq);
        const bool valid = xsq > 1e-12f;            // norm > 1e-6
        const float maskf = valid ? 1.f : 0.f;
        const int idx = row_idx[row];
        const int idxm = valid ? idx : 0;
        const float* w = W + (size_t)idx * DDIM;
        float* oq = out + (size_t)row * DDIM;
        float e2 = 0.f;
#pragma unroll
        for (int j = 0; j < 3; ++j) {
            const float4 wvv = *(const float4*)(w + (lane + 64 * j) * 4);
            const float xs[4] = {xv[j].x, xv[j].y, xv[j].z, xv[j].w};
            const float ws[4] = {wvv.x, wvv.y, wvv.z, wvv.w};
            float os[4];
#pragma unroll
            for (int c = 0; c < 4; ++c) {
                const float q = ws[c] * maskf;          // q_flat = weight[idx] * mask
                os[c] = xs[c] + (q - xs[c]);            // quantized_st
                const float d = xs[c] - q;
                e2 += d * d;
            }
            float4 ov; ov.x = os[0]; ov.y = os[1]; ov.z = os[2]; ov.w = os[3];
            *(float4*)(oq + (lane + 64 * j) * 4) = ov;
        }
        e2 = waveRedAdd(e2);
        if (lane == 0) {
            wsum += (double)(maskf * e2);
            if (valid) {
                ++wval;
                atomicAdd(&counts[idxm], 1.0f);
            }
            out[OUT_IDX + row]  = (float)idxm;
            out[OUT_MIND + row] = valid ? (xsq + row_s[row]) : 0.f;
        }
    }

    if (lane == 0) { s_sum[wid] = wsum; s_val[wid] = wval; }
    __syncthreads();
    if (threadIdx.x == 0) {
        atomicAdd(sum_sqerr, s_sum[0] + s_sum[1] + s_sum[2] + s_sum[3]);
        atomicAdd(n_valid, s_val[0] + s_val[1] + s_val[2] + s_val[3]);
    }
}

// ---------------------------------------------------------------- scalar losses
__global__ __launch_bounds__(256) void k_final(
    const float* __restrict__ counts, const unsigned int* __restrict__ n_valid,
    const double* __restrict__ sum_sqerr, float* __restrict__ out)
{
    const int t = threadIdx.x;
    const float nv = (float)(*n_valid);
    double ent = 0.0;
    for (int k = t; k < KCODES; k += 256) {
        const float p = counts[k] / nv;
        ent += (double)(p * logf(p + 1e-10f));
    }
    ent = waveRedAdd(ent);
    __shared__ double ps[4];
    if ((t & 63) == 0) ps[t >> 6] = ent;
    __syncthreads();
    if (t == 0) {
        const double e = ps[0] + ps[1] + ps[2] + ps[3];
        const double perp = exp(-e);
        const double ploss = -log(perp + 1e-10);
        const double commit = *sum_sqerr / ((double)(*n_valid) * (double)DDIM);
        out[OUT_LOSS] = (float)(0.25 * commit + 0.1 * ploss);
        out[OUT_PERP] = (float)perp;
    }
}

// ----------------------------------------------------------------
extern "C" void kernel_launch(void* const* d_in, const int* in_sizes, int n_in,
                              void* d_out, int out_size, void* d_ws, size_t ws_size,
                              hipStream_t stream) {
    const float* A = (const float*)d_in[0];   // [65536, 768]
    const float* W = (const float*)d_in[1];   // [1024, 768]
    float* out = (float*)d_out;
    char* ws = (char*)d_ws;
    if (ws_size < (size_t)WS_END) return;     // needs >=6.8 MB scratch

    double*   sum_sqerr = (double*)(ws + WS_SUM);
    int*      n_suspect = (int*)(ws + WS_NSUS);
    unsigned* n_valid   = (unsigned*)(ws + WS_NVAL);
    float*    counts    = (float*)(ws + WS_COUNTS);
    float*    wsq       = (float*)(ws + WS_WSQ);
    float*    row_s     = (float*)(ws + WS_ROWS);
    int*      row_idx   = (int*)(ws + WS_ROWI);
    int*      suspects  = (int*)(ws + WS_SUSP);
    float*    pm1       = (float*)(ws + WS_PM1);
    float*    pm2       = (float*)(ws + WS_PM2);
    int*      pidx      = (int*)(ws + WS_PIDX);
    ushort*   Af16      = (ushort*)(ws + WS_AF16);
    ushort*   Wf16      = (ushort*)(ws + WS_WF16);

    const bool big = ws_size >= (size_t)WS_END2;   // ~105 MB: fp16-preconvert path

    hipLaunchKernelGGL(k_init, dim3(1), dim3(256), 0, stream, counts, n_suspect, n_valid, sum_sqerr);
    if (big)
        hipLaunchKernelGGL(k_convert, dim3(2048), dim3(256), 0, stream, A, W, Af16, Wf16);
    hipLaunchKernelGGL(k_wsq, dim3(KCODES), dim3(256), 0, stream, W, wsq);
    if (big)
        hipLaunchKernelGGL(k_partials_g, dim3((NROWS / BM) * NCB), dim3(256), 0, stream, Af16, Wf16, wsq, pm1, pm2, pidx);
    else
        hipLaunchKernelGGL(k_partials, dim3((NROWS / BM) * NCB), dim3(256), 0, stream, A, W, wsq, pm1, pm2, pidx);
    hipLaunchKernelGGL(k_merge, dim3(NROWS / 256), dim3(256), 0, stream, pm1, pm2, pidx, row_s, row_idx, suspects, n_suspect);
    hipLaunchKernelGGL(k_repair, dim3(RGRID), dim3(256), 0, stream, A, W, pm1, suspects, n_suspect, row_s, row_idx);
    hipLaunchKernelGGL(k_quantize, dim3(QGRID), dim3(256), 0, stream, A, W, row_s, row_idx, out, counts, n_valid, sum_sqerr);
    hipLaunchKernelGGL(k_final, dim3(1), dim3(256), 0, stream, counts, n_valid, sum_sqerr, out);
}

// Round 9
// 364.919 us; speedup vs baseline: 18.2861x; 1.0085x over previous
//
#include <hip/hip_runtime.h>
#include <hip/hip_bf16.h>
#include <math.h>

// Problem constants
#define NROWS 65536      // 32*2048
#define DDIM  768
#define KCODES 1024
#define NCB   8          // code blocks (KCODES / BK)
#define BM    128        // rows per block tile
#define BK    128        // codes per block tile
#define KC    32         // K-chunk for fallback kernel
#define NCH   (DDIM / KC)
#define BK2   32         // K-chunk (fp16) for gload_lds kernel
#define NCH2  (DDIM / BK2)
#define PANEL_USH (24 * 4096)   // ushorts per 128-row fp16 panel (24 chunks x 8KB)
#define GAP_TAU  0.3f    // fp16 score-error guard band (~7.5 sigma); near-ties re-checked in fp64
#define FILT_TAU 0.6f    // repair block-filter margin (2x guard band)
#define RGRID 2048       // k_repair blocks
#define QGRID 2048       // k_quantize blocks

// ---- output offsets (d_out is float32, outputs concatenated in return order)
#define OUT_LOSS ((size_t)NROWS * DDIM)
#define OUT_IDX  (OUT_LOSS + 1)
#define OUT_MIND (OUT_IDX + NROWS)
#define OUT_PERP (OUT_MIND + NROWS)

// ---- workspace offsets (bytes)
#define WS_SUM    0                              // double sum_sqerr
#define WS_NSUS   8                              // int n_suspect
#define WS_NVAL   12                             // unsigned n_valid
#define WS_COUNTS 256                            // float[KCODES]
#define WS_WSQ    (WS_COUNTS + 4*KCODES)         // float[KCODES]
#define WS_ROWS   (WS_WSQ + 4*KCODES)            // float[NROWS] row min score (dist - xsq)
#define WS_ROWI   (WS_ROWS + 4*NROWS)            // int[NROWS] row argmin
#define WS_SUSP   (WS_ROWI + 4*NROWS)            // int[NROWS] suspect rows
#define WS_PM1    (WS_SUSP + 4*NROWS)            // float[NROWS*NCB] partial min
#define WS_PM2    (WS_PM1 + (size_t)4*NROWS*NCB) // float[NROWS*NCB] partial 2nd min
#define WS_PIDX   (WS_PM2 + (size_t)4*NROWS*NCB) // int[NROWS*NCB] partial argmin
#define WS_END    (WS_PIDX + (size_t)4*NROWS*NCB)
// fp16 mirrors (tiled LDS-image layout), used only if ws_size permits (~105 MB total)
#define WS_AF16   ((WS_END + 255) & ~(size_t)255)
#define WS_WF16   (WS_AF16 + (size_t)NROWS * DDIM * 2)
#define WS_END2   (WS_WF16 + (size_t)KCODES * DDIM * 2)

typedef __attribute__((ext_vector_type(8))) _Float16 half8;  // 8 f16 = 4 VGPRs (MFMA A/B frag)
typedef __attribute__((ext_vector_type(4))) float f32x4;     // MFMA C/D frag

// async global->LDS, 16B per lane; LDS dest = wave-uniform base + lane*16
#define GLOAD16(gsrc, ldst) \
    __builtin_amdgcn_global_load_lds( \
        (const __attribute__((address_space(1))) unsigned int*)(gsrc), \
        (__attribute__((address_space(3))) unsigned int*)(ldst), 16, 0, 0)

template <typename T>
__device__ inline T waveRedAdd(T v) {
#pragma unroll
    for (int o = 32; o; o >>= 1) v += __shfl_xor(v, o);
    return v;
}

__device__ inline ushort f2h(float f) {
    union { _Float16 h; ushort u; } c;
    c.h = (_Float16)f;   // RTN-even
    return c.u;
}

// ---------------------------------------------------------------- init
__global__ void k_init(float* counts, int* n_suspect, unsigned* n_valid, double* sum_sqerr) {
    const int t = threadIdx.x;
    if (t == 0) { *n_suspect = 0; *n_valid = 0u; *sum_sqerr = 0.0; }
    for (int k = t; k < KCODES; k += 256) counts[k] = 0.f;
}

// ---------------------------------------------------------------- fp32 -> fp16 pre-convert (tiled LDS image)
// Output layout: panel (128 rows) x chunk (32 k) = contiguous 8 KB block laid out EXACTLY
// as the GEMM's LDS tile: byte = r_local*64 + (s ^ ((r>>1)&3))*16. STAGE then loads 1KB
// contiguous segments with zero per-row address math (rule #21: source perm == read perm).
#define ASLOTS (NROWS * (DDIM / 8))
#define TSLOTS ((NROWS + KCODES) * (DDIM / 8))
__global__ __launch_bounds__(256) void k_convert(
    const float* __restrict__ A, const float* __restrict__ W,
    ushort* __restrict__ Af16, ushort* __restrict__ Wf16)
{
    for (int gidx = blockIdx.x * 256 + threadIdx.x; gidx < TSLOTS; gidx += gridDim.x * 256) {
        const float* src; ushort* dst; int sid;
        if (gidx < ASLOTS) { src = A; dst = Af16; sid = gidx; }
        else { src = W; dst = Wf16; sid = gidx - ASLOTS; }
        const int row = sid / 96;           // 96 slots per row
        const int sl = sid - row * 96;
        const int ch = sl >> 2, s = sl & 3; // 24 chunks x 4 slots of 16B
        const float* p = src + (size_t)row * DDIM + ch * 32 + s * 8;
        const float4 a = *(const float4*)p;
        const float4 b = *(const float4*)(p + 4);
        uint4 v;
        v.x = ((unsigned)f2h(a.y) << 16) | f2h(a.x);
        v.y = ((unsigned)f2h(a.w) << 16) | f2h(a.z);
        v.z = ((unsigned)f2h(b.y) << 16) | f2h(b.x);
        v.w = ((unsigned)f2h(b.w) << 16) | f2h(b.z);
        // (row>>1)&3 == (r_local>>1)&3 since panel*128 is a multiple of 8
        const size_t dsti = (size_t)(row >> 7) * PANEL_USH + ch * 4096
                          + (row & 127) * 32 + ((s ^ ((row >> 1) & 3)) << 3);
        *(uint4*)(dst + dsti) = v;
    }
}

// ---------------------------------------------------------------- ||e_k||^2 (exact fp32)
__global__ __launch_bounds__(256) void k_wsq(const float* __restrict__ W, float* __restrict__ wsq) {
    const int k = blockIdx.x;
    const int t = threadIdx.x;
    const float* w = W + (size_t)k * DDIM;
    const float a = w[t], b = w[t + 256], c = w[t + 512];
    float s = a * a + b * b + c * c;
    s = waveRedAdd(s);
    __shared__ float p[4];
    if ((t & 63) == 0) p[t >> 6] = s;
    __syncthreads();
    if (t == 0) wsq[k] = (p[0] + p[1]) + (p[2] + p[3]);
}

// ---------------------------------------------------------------- main GEMM (fp16 MFMA, tiled gload_lds, dbuf)
// 128x128 tile, BK2=32, double-buffered 32 KB LDS, 4 blocks/CU. STAGE loads contiguous
// 1 KB segments from the pre-tiled fp16 panels (one pointer bump per chunk). unroll 2
// makes `cur` compile-time so all LDS read addresses hoist out of the loop.
__global__ __launch_bounds__(256, 4) void k_partials_g(
    const ushort* __restrict__ Af16, const ushort* __restrict__ Wf16,
    const float* __restrict__ wsq,
    float* __restrict__ pm1, float* __restrict__ pm2, int* __restrict__ pidx)
{
    __shared__ __align__(16) ushort lds[2 * 2 * BM * BK2];   // [buf][A|W][8KB] = 32 KB

    // XCD-panel swizzle: each XCD owns a contiguous band of 64 row-panels, cb fastest.
    const int bid = blockIdx.x;
    const int rb = ((bid & 7) << 6) | (bid >> 6);
    const int cb = (bid >> 3) & 7;

    const int tid = threadIdx.x;
    const int wid = tid >> 6, lane = tid & 63;
    const int wr = wid >> 1, wc = wid & 1;       // wave quadrant (row-half, col-half)
    const int l15 = lane & 15, g = lane >> 4;    // frag row/col + k-group (0..3, 8 f16 each)

    const ushort* Ap = Af16 + (size_t)rb * PANEL_USH;   // tiled panel base
    const ushort* Wp = Wf16 + (size_t)cb * PANEL_USH;

    // within-buffer LDS read offsets (ushorts), loop-invariant
    int aoff[4], boff[4];
#pragma unroll
    for (int rt = 0; rt < 4; ++rt) {
        const int r = wr * 64 + rt * 16 + l15;
        aoff[rt] = r * 32 + ((g ^ ((r >> 1) & 3)) << 3);
        const int c = wc * 64 + rt * 16 + l15;
        boff[rt] = c * 32 + ((g ^ ((c >> 1) & 3)) << 3);
    }

    f32x4 acc[4][4];
#pragma unroll
    for (int rt = 0; rt < 4; ++rt)
#pragma unroll
        for (int ct = 0; ct < 4; ++ct) acc[rt][ct] = (f32x4)0.f;

    const int lseg = lane << 3;   // lane*16B in ushorts
    auto STAGE = [&](int ch, int b) {
        ushort* As = lds + b * 8192;
        ushort* Ws = As + 4096;
        const ushort* Asrc = Ap + ch * 4096;
        const ushort* Wsrc = Wp + ch * 4096;
        // two 1KB segments per wave for A and W (seg = wid and wid+4)
        GLOAD16(Asrc + (wid << 9) + lseg,       (char*)As + (wid << 10));
        GLOAD16(Asrc + ((wid + 4) << 9) + lseg, (char*)As + ((wid + 4) << 10));
        GLOAD16(Wsrc + (wid << 9) + lseg,       (char*)Ws + (wid << 10));
        GLOAD16(Wsrc + ((wid + 4) << 9) + lseg, (char*)Ws + ((wid + 4) << 10));
    };

    STAGE(0, 0);
    __syncthreads();   // implicit vmcnt(0): buf0 staged

#pragma unroll 2
    for (int ch = 0; ch < NCH2; ++ch) {
        const int cur = ch & 1;   // compile-time under unroll 2
        if (ch + 1 < NCH2) STAGE(ch + 1, cur ^ 1);   // async; lands during compute
        const ushort* As = lds + cur * 8192;
        const ushort* Ws = As + 4096;
        half8 bf[4];
#pragma unroll
        for (int ct = 0; ct < 4; ++ct) bf[ct] = *(const half8*)(Ws + boff[ct]);
#pragma unroll
        for (int rt = 0; rt < 4; ++rt) {
            const half8 af = *(const half8*)(As + aoff[rt]);
#pragma unroll
            for (int ct = 0; ct < 4; ++ct)
                acc[rt][ct] = __builtin_amdgcn_mfma_f32_16x16x32_f16(af, bf[ct], acc[rt][ct], 0, 0, 0);
        }
        __syncthreads();   // drains vmcnt(0) -> next buf ready; cur buf free to overwrite
    }

    // ---------------- epilogue: per-row (min, 2nd-min, argmin) over this 128-code tile
    // C/D layout: col = lane&15, row = (lane>>4)*4 + q  [m89]
    float wq[4];
#pragma unroll
    for (int ct = 0; ct < 4; ++ct) wq[ct] = wsq[cb * BK + wc * 64 + ct * 16 + l15];
    const int cbase = cb * BK + wc * 64 + l15;

    float* tm1 = (float*)lds;          // [128][2]  (row-local, wc) — loop barrier already passed
    float* tm2 = tm1 + 256;
    int*   ti1 = (int*)(tm2 + 256);

#pragma unroll
    for (int rt = 0; rt < 4; ++rt) {
        float m1q[4], m2q[4]; int i1q[4];
#pragma unroll
        for (int q = 0; q < 4; ++q) { m1q[q] = INFINITY; m2q[q] = INFINITY; i1q[q] = 0x7fffffff; }
#pragma unroll
        for (int ct = 0; ct < 4; ++ct) {
            const int col = cbase + ct * 16;
#pragma unroll
            for (int q = 0; q < 4; ++q) {
                const float s = fmaf(-2.f, acc[rt][ct][q], wq[ct]);
                if (s < m1q[q]) { m2q[q] = m1q[q]; m1q[q] = s; i1q[q] = col; }
                else if (s < m2q[q]) m2q[q] = s;
            }
        }
#pragma unroll
        for (int msk = 1; msk <= 8; msk <<= 1) {
#pragma unroll
            for (int q = 0; q < 4; ++q) {
                const float om1 = __shfl_xor(m1q[q], msk);
                const float om2 = __shfl_xor(m2q[q], msk);
                const int   oi1 = __shfl_xor(i1q[q], msk);
                if (om1 < m1q[q] || (om1 == m1q[q] && oi1 < i1q[q])) {
                    m2q[q] = fminf(m1q[q], om2); m1q[q] = om1; i1q[q] = oi1;
                } else m2q[q] = fminf(m2q[q], om1);
            }
        }
        if (l15 == 0) {
#pragma unroll
            for (int q = 0; q < 4; ++q) {
                const int rl = wr * 64 + rt * 16 + g * 4 + q;   // row within block
                tm1[rl * 2 + wc] = m1q[q];
                tm2[rl * 2 + wc] = m2q[q];
                ti1[rl * 2 + wc] = i1q[q];
            }
        }
    }
    __syncthreads();
    if (tid < BM) {
        float m1 = tm1[tid * 2], m2 = tm2[tid * 2]; int i1 = ti1[tid * 2];
        const float bm1 = tm1[tid * 2 + 1], bm2 = tm2[tid * 2 + 1]; const int bi = ti1[tid * 2 + 1];
        if (bm1 < m1 || (bm1 == m1 && bi < i1)) { m2 = fminf(m1, bm2); m1 = bm1; i1 = bi; }
        else m2 = fminf(m2, bm1);
        const size_t row = (size_t)rb * BM + tid;
        pm1[row * NCB + cb] = m1;
        pm2[row * NCB + cb] = m2;
        pidx[row * NCB + cb] = i1;
    }
}

// ---------------------------------------------------------------- fallback GEMM (fused cvt) if ws too small
__global__ __launch_bounds__(256, 2) void k_partials(
    const float* __restrict__ A, const float* __restrict__ W,
    const float* __restrict__ wsq,
    float* __restrict__ pm1, float* __restrict__ pm2, int* __restrict__ pidx)
{
    __shared__ __align__(16) ushort lds[2 * BM * KC];
    ushort* As = lds;
    ushort* Ws = lds + BM * KC;

    const int bid = blockIdx.x;
    const int rb = ((bid & 7) << 6) | (bid >> 6);
    const int cb = (bid >> 3) & 7;

    const int tid = threadIdx.x;
    const int wid = tid >> 6, lane = tid & 63;
    const int wr = wid >> 1, wc = wid & 1;
    const int l15 = lane & 15, g = lane >> 4;

    const float* Ab = A + (size_t)rb * BM * DDIM;
    const float* Wb = W + (size_t)cb * BK * DDIM;

    const int srow = tid >> 3;
    const int sk4  = (tid & 7) << 2;
    const int sg   = (tid & 7) >> 1;
    const int sh   = (tid & 1) << 2;

    int aOff[4], bOff[4];
#pragma unroll
    for (int rt = 0; rt < 4; ++rt) {
        const int r = wr * 64 + rt * 16 + l15;
        aOff[rt] = r * KC + ((g ^ ((r >> 1) & 3)) << 3);
        const int c = wc * 64 + rt * 16 + l15;
        bOff[rt] = c * KC + ((g ^ ((c >> 1) & 3)) << 3);
    }

    f32x4 acc[4][4];
#pragma unroll
    for (int rt = 0; rt < 4; ++rt)
#pragma unroll
        for (int ct = 0; ct < 4; ++ct) acc[rt][ct] = (f32x4)0.f;

    float4 av[4], wv[4];
#pragma unroll
    for (int i = 0; i < 4; ++i) {
        av[i] = *(const float4*)(Ab + (size_t)(srow + 32 * i) * DDIM + sk4);
        wv[i] = *(const float4*)(Wb + (size_t)(srow + 32 * i) * DDIM + sk4);
    }

#pragma unroll 1
    for (int ch = 0; ch < NCH; ++ch) {
        __syncthreads();
#pragma unroll
        for (int i = 0; i < 4; ++i) {
            const int r = srow + 32 * i;
            const int wsl = r * KC + ((sg ^ ((r >> 1) & 3)) << 3) + sh;
            ushort4 ua; ua.x = f2h(av[i].x); ua.y = f2h(av[i].y); ua.z = f2h(av[i].z); ua.w = f2h(av[i].w);
            *(ushort4*)(As + wsl) = ua;
            ushort4 uw; uw.x = f2h(wv[i].x); uw.y = f2h(wv[i].y); uw.z = f2h(wv[i].z); uw.w = f2h(wv[i].w);
            *(ushort4*)(Ws + wsl) = uw;
        }
        __syncthreads();
        if (ch + 1 < NCH) {
            const int d0 = (ch + 1) * KC + sk4;
#pragma unroll
            for (int i = 0; i < 4; ++i) {
                av[i] = *(const float4*)(Ab + (size_t)(srow + 32 * i) * DDIM + d0);
                wv[i] = *(const float4*)(Wb + (size_t)(srow + 32 * i) * DDIM + d0);
            }
        }
        half8 af[4], bf[4];
#pragma unroll
        for (int rt = 0; rt < 4; ++rt) af[rt] = *(const half8*)(As + aOff[rt]);
#pragma unroll
        for (int ct = 0; ct < 4; ++ct) bf[ct] = *(const half8*)(Ws + bOff[ct]);
#pragma unroll
        for (int rt = 0; rt < 4; ++rt)
#pragma unroll
            for (int ct = 0; ct < 4; ++ct)
                acc[rt][ct] = __builtin_amdgcn_mfma_f32_16x16x32_f16(af[rt], bf[ct], acc[rt][ct], 0, 0, 0);
    }

    float wq[4];
#pragma unroll
    for (int ct = 0; ct < 4; ++ct) wq[ct] = wsq[cb * BK + wc * 64 + ct * 16 + l15];
    const int cbase = cb * BK + wc * 64 + l15;

    __syncthreads();
    float* tm1 = (float*)lds;
    float* tm2 = tm1 + 256;
    int*   ti1 = (int*)(tm2 + 256);

#pragma unroll
    for (int rt = 0; rt < 4; ++rt) {
        float m1q[4], m2q[4]; int i1q[4];
#pragma unroll
        for (int q = 0; q < 4; ++q) { m1q[q] = INFINITY; m2q[q] = INFINITY; i1q[q] = 0x7fffffff; }
#pragma unroll
        for (int ct = 0; ct < 4; ++ct) {
            const int col = cbase + ct * 16;
#pragma unroll
            for (int q = 0; q < 4; ++q) {
                const float s = fmaf(-2.f, acc[rt][ct][q], wq[ct]);
                if (s < m1q[q]) { m2q[q] = m1q[q]; m1q[q] = s; i1q[q] = col; }
                else if (s < m2q[q]) m2q[q] = s;
            }
        }
#pragma unroll
        for (int msk = 1; msk <= 8; msk <<= 1) {
#pragma unroll
            for (int q = 0; q < 4; ++q) {
                const float om1 = __shfl_xor(m1q[q], msk);
                const float om2 = __shfl_xor(m2q[q], msk);
                const int   oi1 = __shfl_xor(i1q[q], msk);
                if (om1 < m1q[q] || (om1 == m1q[q] && oi1 < i1q[q])) {
                    m2q[q] = fminf(m1q[q], om2); m1q[q] = om1; i1q[q] = oi1;
                } else m2q[q] = fminf(m2q[q], om1);
            }
        }
        if (l15 == 0) {
#pragma unroll
            for (int q = 0; q < 4; ++q) {
                const int rl = wr * 64 + rt * 16 + g * 4 + q;
                tm1[rl * 2 + wc] = m1q[q];
                tm2[rl * 2 + wc] = m2q[q];
                ti1[rl * 2 + wc] = i1q[q];
            }
        }
    }
    __syncthreads();
    if (tid < BM) {
        float m1 = tm1[tid * 2], m2 = tm2[tid * 2]; int i1 = ti1[tid * 2];
        const float bm1 = tm1[tid * 2 + 1], bm2 = tm2[tid * 2 + 1]; const int bi = ti1[tid * 2 + 1];
        if (bm1 < m1 || (bm1 == m1 && bi < i1)) { m2 = fminf(m1, bm2); m1 = bm1; i1 = bi; }
        else m2 = fminf(m2, bm1);
        const size_t row = (size_t)rb * BM + tid;
        pm1[row * NCB + cb] = m1;
        pm2[row * NCB + cb] = m2;
        pidx[row * NCB + cb] = i1;
    }
}

// ---------------------------------------------------------------- merge 8 partials per row
__global__ __launch_bounds__(256) void k_merge(
    const float* __restrict__ pm1, const float* __restrict__ pm2, const int* __restrict__ pidx,
    float* __restrict__ row_s, int* __restrict__ row_idx,
    int* __restrict__ suspects, int* __restrict__ n_suspect)
{
    const int row = blockIdx.x * 256 + threadIdx.x;
    float m1 = INFINITY, m2 = INFINITY; int i1 = 0x7fffffff;
#pragma unroll
    for (int cb = 0; cb < NCB; ++cb) {
        const float bm1 = pm1[(size_t)row * NCB + cb];
        const float bm2 = pm2[(size_t)row * NCB + cb];
        const int   bi  = pidx[(size_t)row * NCB + cb];
        if (bm1 < m1 || (bm1 == m1 && bi < i1)) { m2 = fminf(m1, bm2); m1 = bm1; i1 = bi; }
        else m2 = fminf(m2, bm1);
    }
    row_s[row] = m1;
    row_idx[row] = i1;
    if (m2 - m1 < GAP_TAU) {   // fp16 noise could have reordered: exact re-check
        const int p = atomicAdd(n_suspect, 1);
        suspects[p] = row;
    }
}

// ---------------------------------------------------------------- fp64 re-check of near-ties
__global__ __launch_bounds__(256) void k_repair(
    const float* __restrict__ A, const float* __restrict__ W,
    const float* __restrict__ pm1,
    const int* __restrict__ suspects, const int* __restrict__ n_suspect,
    float* __restrict__ row_s, int* __restrict__ row_idx)
{
    __shared__ __align__(16) float xrow[DDIM];
    __shared__ double wbest[4]; __shared__ int wbi[4];
    __shared__ double xps[4];
    __shared__ int qcb[NCB];
    __shared__ int nq;
    const int ns = *n_suspect;
    const int tid = threadIdx.x;
    const int wid = tid >> 6, lane = tid & 63;
    const int sub = tid & 3;        // 16B stripe within a code
    const int cq  = tid >> 2;       // code slot 0..63

    for (int s = blockIdx.x; s < ns; s += gridDim.x) {
        const int row = suspects[s];
        __syncthreads();   // previous iteration done with shared
        xrow[tid]       = A[(size_t)row * DDIM + tid];
        xrow[tid + 256] = A[(size_t)row * DDIM + tid + 256];
        xrow[tid + 512] = A[(size_t)row * DDIM + tid + 512];
        if (tid == 0) {
            float gmin = INFINITY;
#pragma unroll
            for (int cb = 0; cb < NCB; ++cb) gmin = fminf(gmin, pm1[(size_t)row * NCB + cb]);
            int n = 0;
#pragma unroll
            for (int cb = 0; cb < NCB; ++cb)
                if (pm1[(size_t)row * NCB + cb] <= gmin + FILT_TAU) qcb[n++] = cb;
            nq = n;
        }
        __syncthreads();

        // xsq in fp64 (per-wave stripes combined at the end)
        double xp = 0.0;
        {
            double t;
            t = (double)xrow[tid];       xp = fma(t, t, xp);
            t = (double)xrow[tid + 256]; xp = fma(t, t, xp);
            t = (double)xrow[tid + 512]; xp = fma(t, t, xp);
        }
        xp = waveRedAdd(xp);
        if (lane == 0) xps[wid] = xp;

        double best = 1e300; int bi = 0x7fffffff;
        const int ncand = nq * BK;
        for (int base = 0; base < ncand; base += 64) {
            const int ci = base + cq;
            const bool act = ci < ncand;       // uniform within a quad
            double d = 0.0; int k = 0x7fffffff;
            if (act) {
                k = qcb[ci >> 7] * BK + (ci & (BK - 1));
                const float* wr = W + (size_t)k * DDIM + (sub << 2);
                const float* xr = xrow + (sub << 2);
                double d0 = 0.0, d1 = 0.0;
                for (int i = 0; i < DDIM; i += 16) {
                    const float4 wv = *(const float4*)(wr + i);
                    const float4 xv = *(const float4*)(xr + i);
                    double t;
                    t = (double)xv.x - (double)wv.x; d0 = fma(t, t, d0);
                    t = (double)xv.y - (double)wv.y; d1 = fma(t, t, d1);
                    t = (double)xv.z - (double)wv.z; d0 = fma(t, t, d0);
                    t = (double)xv.w - (double)wv.w; d1 = fma(t, t, d1);
                }
                d = d0 + d1;
            }
            d += __shfl_xor(d, 1);   // combine the 4 stripes of this code
            d += __shfl_xor(d, 2);
            if (act && sub == 0) {
                if (d < best || (d == best && k < bi)) { best = d; bi = k; }
            }
        }
        // wave butterfly (non-leaders hold +inf)
#pragma unroll
        for (int o = 32; o; o >>= 1) {
            const double ob = __shfl_xor(best, o);
            const int oi = __shfl_xor(bi, o);
            if (ob < best || (ob == best && oi < bi)) { best = ob; bi = oi; }
        }
        if (lane == 0) { wbest[wid] = best; wbi[wid] = bi; }
        __syncthreads();
        if (tid == 0) {
            double b = wbest[0]; int i1 = wbi[0];
#pragma unroll
            for (int w = 1; w < 4; ++w)
                if (wbest[w] < b || (wbest[w] == b && wbi[w] < i1)) { b = wbest[w]; i1 = wbi[w]; }
            row_idx[row] = i1;
            row_s[row] = (float)(b - (xps[0] + xps[1] + xps[2] + xps[3]));   // score form (dist - xsq)
        }
    }
}

// ---------------------------------------------------------------- quantize + losses + idx/min_d outputs
__global__ __launch_bounds__(256) void k_quantize(
    const float* __restrict__ A, const float* __restrict__ W,
    const float* __restrict__ row_s, const int* __restrict__ row_idx,
    float* __restrict__ out, float* __restrict__ counts,
    unsigned int* __restrict__ n_valid, double* __restrict__ sum_sqerr)
{
    const int wid = threadIdx.x >> 6, lane = threadIdx.x & 63;
    __shared__ double s_sum[4];
    __shared__ unsigned s_val[4];
    double wsum = 0.0; unsigned wval = 0;

#pragma unroll 1
    for (int it = 0; it < NROWS / (QGRID * 4); ++it) {
        const int row = (it * QGRID + blockIdx.x) * 4 + wid;
        const float* x = A + (size_t)row * DDIM;
        float4 xv[3];
#pragma unroll
        for (int j = 0; j < 3; ++j) xv[j] = *(const float4*)(x + (lane + 64 * j) * 4);
        float xsq = 0.f;
#pragma unroll
        for (int j = 0; j < 3; ++j)
            xsq += xv[j].x * xv[j].x + xv[j].y * xv[j].y + xv[j].z * xv[j].z + xv[j].w * xv[j].w;
        xsq = waveRedAdd(xsq);
        const bool valid = xsq > 1e-12f;            // norm > 1e-6
        const float maskf = valid ? 1.f : 0.f;
        const int idx = row_idx[row];
        const int idxm = valid ? idx : 0;
        const float* w = W + (size_t)idx * DDIM;
        float* oq = out + (size_t)row * DDIM;
        float e2 = 0.f;
#pragma unroll
        for (int j = 0; j < 3; ++j) {
            const float4 wvv = *(const float4*)(w + (lane + 64 * j) * 4);
            const float xs[4] = {xv[j].x, xv[j].y, xv[j].z, xv[j].w};
            const float ws[4] = {wvv.x, wvv.y, wvv.z, wvv.w};
            float os[4];
#pragma unroll
            for (int c = 0; c < 4; ++c) {
                const float q = ws[c] * maskf;          // q_flat = weight[idx] * mask
                os[c] = xs[c] + (q - xs[c]);            // quantized_st
                const float d = xs[c] - q;
                e2 += d * d;
            }
            float4 ov; ov.x = os[0]; ov.y = os[1]; ov.z = os[2]; ov.w = os[3];
            *(float4*)(oq + (lane + 64 * j) * 4) = ov;
        }
        e2 = waveRedAdd(e2);
        if (lane == 0) {
            wsum += (double)(maskf * e2);
            if (valid) {
                ++wval;
                atomicAdd(&counts[idxm], 1.0f);
            }
            out[OUT_IDX + row]  = (float)idxm;
            out[OUT_MIND + row] = valid ? (xsq + row_s[row]) : 0.f;
        }
    }

    if (lane == 0) { s_sum[wid] = wsum; s_val[wid] = wval; }
    __syncthreads();
    if (threadIdx.x == 0) {
        atomicAdd(sum_sqerr, s_sum[0] + s_sum[1] + s_sum[2] + s_sum[3]);
        atomicAdd(n_valid, s_val[0] + s_val[1] + s_val[2] + s_val[3]);
    }
}

// ---------------------------------------------------------------- scalar losses
__global__ __launch_bounds__(256) void k_final(
    const float* __restrict__ counts, const unsigned int* __restrict__ n_valid,
    const double* __restrict__ sum_sqerr, float* __restrict__ out)
{
    const int t = threadIdx.x;
    const float nv = (float)(*n_valid);
    double ent = 0.0;
    for (int k = t; k < KCODES; k += 256) {
        const float p = counts[k] / nv;
        ent += (double)(p * logf(p + 1e-10f));
    }
    ent = waveRedAdd(ent);
    __shared__ double ps[4];
    if ((t & 63) == 0) ps[t >> 6] = ent;
    __syncthreads();
    if (t == 0) {
        const double e = ps[0] + ps[1] + ps[2] + ps[3];
        const double perp = exp(-e);
        const double ploss = -log(perp + 1e-10);
        const double commit = *sum_sqerr / ((double)(*n_valid) * (double)DDIM);
        out[OUT_LOSS] = (float)(0.25 * commit + 0.1 * ploss);
        out[OUT_PERP] = (float)perp;
    }
}

// ----------------------------------------------------------------
extern "C" void kernel_launch(void* const* d_in, const int* in_sizes, int n_in,
                              void* d_out, int out_size, void* d_ws, size_t ws_size,
                              hipStream_t stream) {
    const float* A = (const float*)d_in[0];   // [65536, 768]
    const float* W = (const float*)d_in[1];   // [1024, 768]
    float* out = (float*)d_out;
    char* ws = (char*)d_ws;
    if (ws_size < (size_t)WS_END) return;     // needs >=6.8 MB scratch

    double*   sum_sqerr = (double*)(ws + WS_SUM);
    int*      n_suspect = (int*)(ws + WS_NSUS);
    unsigned* n_valid   = (unsigned*)(ws + WS_NVAL);
    float*    counts    = (float*)(ws + WS_COUNTS);
    float*    wsq       = (float*)(ws + WS_WSQ);
    float*    row_s     = (float*)(ws + WS_ROWS);
    int*      row_idx   = (int*)(ws + WS_ROWI);
    int*      suspects  = (int*)(ws + WS_SUSP);
    float*    pm1       = (float*)(ws + WS_PM1);
    float*    pm2       = (float*)(ws + WS_PM2);
    int*      pidx      = (int*)(ws + WS_PIDX);
    ushort*   Af16      = (ushort*)(ws + WS_AF16);
    ushort*   Wf16      = (ushort*)(ws + WS_WF16);

    const bool big = ws_size >= (size_t)WS_END2;   // ~105 MB: fp16-preconvert path

    hipLaunchKernelGGL(k_init, dim3(1), dim3(256), 0, stream, counts, n_suspect, n_valid, sum_sqerr);
    if (big)
        hipLaunchKernelGGL(k_convert, dim3(2048), dim3(256), 0, stream, A, W, Af16, Wf16);
    hipLaunchKernelGGL(k_wsq, dim3(KCODES), dim3(256), 0, stream, W, wsq);
    if (big)
        hipLaunchKernelGGL(k_partials_g, dim3((NROWS / BM) * NCB), dim3(256), 0, stream, Af16, Wf16, wsq, pm1, pm2, pidx);
    else
        hipLaunchKernelGGL(k_partials, dim3((NROWS / BM) * NCB), dim3(256), 0, stream, A, W, wsq, pm1, pm2, pidx);
    hipLaunchKernelGGL(k_merge, dim3(NROWS / 256), dim3(256), 0, stream, pm1, pm2, pidx, row_s, row_idx, suspects, n_suspect);
    hipLaunchKernelGGL(k_repair, dim3(RGRID), dim3(256), 0, stream, A, W, pm1, suspects, n_suspect, row_s, row_idx);
    hipLaunchKernelGGL(k_quantize, dim3(QGRID), dim3(256), 0, stream, A, W, row_s, row_idx, out, counts, n_valid, sum_sqerr);
    hipLaunchKernelGGL(k_final, dim3(1), dim3(256), 0, stream, counts, n_valid, sum_sqerr, out);
}